// Round 5
// baseline (413.616 us; speedup 1.0000x reference)
//
#include <hip/hip_runtime.h>

#define NN 100000
#define NB 512            // buckets
#define NPB 196           // nodes per bucket: ceil(100000/512)=196; local dst fits in 8 bits

__device__ inline unsigned short f2bf(float f) {
    unsigned u = __float_as_uint(f);
    unsigned r = (u + 0x7FFFu + ((u >> 16) & 1u)) >> 16;
    return (unsigned short)r;
}

// accumulate 4 bf16 (packed in uint2) into float4
__device__ inline void bfacc(uint2 u, float4& a) {
    a.x += __uint_as_float(u.x << 16);
    a.y += __uint_as_float(u.x & 0xFFFF0000u);
    a.z += __uint_as_float(u.y << 16);
    a.w += __uint_as_float(u.y & 0xFFFF0000u);
}
__device__ inline float4 bf4(uint2 u) {
    return make_float4(__uint_as_float(u.x << 16), __uint_as_float(u.x & 0xFFFF0000u),
                       __uint_as_float(u.y << 16), __uint_as_float(u.y & 0xFFFF0000u));
}

// ---------------- CSR build: 2-level bucket multisplit ----------------

__global__ __launch_bounds__(256) void bcount_kernel(const int* __restrict__ dst, int E, int* __restrict__ bcnt) {
    __shared__ int h[NB];
    for (int i = threadIdx.x; i < NB; i += 256) h[i] = 0;
    __syncthreads();
    for (int e = blockIdx.x * 256 + threadIdx.x; e < E; e += gridDim.x * 256)
        atomicAdd(&h[dst[e] / NPB], 1);
    __syncthreads();
    for (int i = threadIdx.x; i < NB; i += 256)
        if (h[i]) atomicAdd(&bcnt[i], h[i]);
}

__global__ __launch_bounds__(512) void bscan_kernel(const int* __restrict__ bcnt, int* __restrict__ bstart,
                                                    int* __restrict__ cursors, int E) {
    __shared__ int sh[NB];
    int t = threadIdx.x;
    int v = bcnt[t];
    sh[t] = v;
    __syncthreads();
    for (int off = 1; off < NB; off <<= 1) {
        int u = (t >= off) ? sh[t - off] : 0;
        __syncthreads();
        sh[t] += u;
        __syncthreads();
    }
    int ex = sh[t] - v;
    bstart[t] = ex;
    cursors[t] = ex;
    if (t == NB - 1) bstart[NB] = E;
}

__global__ __launch_bounds__(256) void multisplit_kernel(const int* __restrict__ src, const int* __restrict__ dst,
                                                         int E, int* __restrict__ cursors,
                                                         unsigned int* __restrict__ packed) {
    __shared__ int cnt[NB];
    __shared__ int base[NB];
    const int CH = 256 * 16;
    int t = threadIdx.x;
    for (long c0 = (long)blockIdx.x * CH; c0 < E; c0 += (long)gridDim.x * CH) {
        for (int i = t; i < NB; i += 256) cnt[i] = 0;
        __syncthreads();
        int s[16], d[16];
        #pragma unroll
        for (int k = 0; k < 16; ++k) {
            long e = c0 + k * 256 + t;
            if (e < E) {
                d[k] = dst[e];
                s[k] = src[e];
                atomicAdd(&cnt[d[k] / NPB], 1);
            } else d[k] = -1;
        }
        __syncthreads();
        for (int i = t; i < NB; i += 256)
            base[i] = cnt[i] ? atomicAdd(&cursors[i], cnt[i]) : 0;
        __syncthreads();
        #pragma unroll
        for (int k = 0; k < 16; ++k) {
            if (d[k] >= 0) {
                int b = d[k] / NPB;
                int ld = d[k] - b * NPB;
                int pos = atomicAdd(&base[b], 1);
                packed[pos] = ((unsigned int)s[k] << 8) | (unsigned int)ld;
            }
        }
        __syncthreads();
    }
}

__global__ __launch_bounds__(256) void bucket_fill_kernel(const unsigned int* __restrict__ packed,
                                                          const int* __restrict__ bstart, int N, int E,
                                                          int* __restrict__ rowptr, int* __restrict__ col,
                                                          float* __restrict__ dinv) {
    int b = blockIdx.x, t = threadIdx.x;
    int e0 = bstart[b], e1 = bstart[b + 1];
    __shared__ int hist[256];
    __shared__ int sh[256];
    __shared__ int cur[256];
    hist[t] = 0;
    __syncthreads();
    for (int e = e0 + t; e < e1; e += 256)
        atomicAdd(&hist[packed[e] & 255u], 1);
    __syncthreads();
    int v = hist[t];
    sh[t] = v;
    __syncthreads();
    for (int off = 1; off < 256; off <<= 1) {
        int u = (t >= off) ? sh[t - off] : 0;
        __syncthreads();
        sh[t] += u;
        __syncthreads();
    }
    int ex = sh[t] - v;
    int node = b * NPB + t;
    if (t < NPB && node < N) {
        rowptr[node] = e0 + ex;
        dinv[node] = rsqrtf(1.0f + (float)v);
    }
    cur[t] = e0 + ex;
    __syncthreads();
    for (int e = e0 + t; e < e1; e += 256) {
        unsigned int p = packed[e];
        int pos = atomicAdd(&cur[p & 255u], 1);
        col[pos] = (int)(p >> 8);
    }
    if (b == 0 && t == 0) rowptr[N] = E;
}

// ---------------- GEMM (single output, bf16 out, optionally slice-major [C/16][N][16]) ----------------

template <int K, int C, bool SLICED>
__global__ __launch_bounds__(256) void gemm_kernel(const float* __restrict__ X, const float* __restrict__ W,
                                                   const float* __restrict__ bias, const float* __restrict__ scale,
                                                   unsigned short* __restrict__ out, int N) {
    constexpr int MC = C / 16;
    constexpr int XS = K + 4;
    __shared__ float XL[64 * XS];
    __shared__ float WL[K * C];
    int t = threadIdx.x;
    int r0 = blockIdx.x * 64;

    for (int i = t; i < K * C / 4; i += 256)
        ((float4*)WL)[i] = ((const float4*)W)[i];

    constexpr int RV = K / 4;
    for (int i = t; i < 64 * RV; i += 256) {
        int row = i / RV, c4 = i % RV;
        float4 v = make_float4(0.f, 0.f, 0.f, 0.f);
        if (r0 + row < N) v = ((const float4*)(X + (long)(r0 + row) * K))[c4];
        *(float4*)&XL[row * XS + c4 * 4] = v;
    }
    __syncthreads();

    int ty = t >> 4, tx = t & 15;
    float acc[4][MC];
    #pragma unroll
    for (int i = 0; i < 4; ++i)
        #pragma unroll
        for (int j = 0; j < MC; ++j) acc[i][j] = 0.f;

    const float* xb = &XL[(ty * 4) * XS];
    const float* wb = &WL[tx * MC];
    for (int k = 0; k < K; ++k) {
        float x0 = xb[k], x1 = xb[XS + k], x2 = xb[2 * XS + k], x3 = xb[3 * XS + k];
        float w[MC];
        #pragma unroll
        for (int j = 0; j < MC; ++j) w[j] = wb[k * C + j];
        #pragma unroll
        for (int j = 0; j < MC; ++j) {
            acc[0][j] = fmaf(x0, w[j], acc[0][j]);
            acc[1][j] = fmaf(x1, w[j], acc[1][j]);
            acc[2][j] = fmaf(x2, w[j], acc[2][j]);
            acc[3][j] = fmaf(x3, w[j], acc[3][j]);
        }
    }

    #pragma unroll
    for (int i = 0; i < 4; ++i) {
        int row = r0 + ty * 4 + i;
        if (row < N) {
            float sc = scale ? scale[row] : 1.0f;
            #pragma unroll
            for (int j = 0; j < MC; ++j) {
                int c = tx * MC + j;
                float v = acc[i][j] * sc;
                if (bias) v += bias[c];
                long idx = SLICED ? (((long)(c >> 4) * N + row) * 16 + (c & 15))
                                  : ((long)row * C + c);
                out[idx] = f2bf(v);
            }
        }
    }
}

// ---------------- GEMM (two bf16 outputs sharing one X pass) ----------------

template <int K, int C1, int C2, bool A_SLICED>
__global__ __launch_bounds__(256) void gemm2_kernel(const float* __restrict__ X,
                                                    const float* __restrict__ Wa, const float* __restrict__ ba,
                                                    const float* __restrict__ scale,
                                                    const float* __restrict__ Wb, const float* __restrict__ bb,
                                                    unsigned short* __restrict__ outa,
                                                    unsigned short* __restrict__ outb, int N) {
    constexpr int M1 = C1 / 16, M2 = C2 / 16;
    constexpr int XS = K + 4;
    __shared__ float XL[64 * XS];
    __shared__ float WLa[K * C1];
    __shared__ float WLb[K * C2];
    int t = threadIdx.x;
    int r0 = blockIdx.x * 64;

    for (int i = t; i < K * C1 / 4; i += 256) ((float4*)WLa)[i] = ((const float4*)Wa)[i];
    for (int i = t; i < K * C2 / 4; i += 256) ((float4*)WLb)[i] = ((const float4*)Wb)[i];

    constexpr int RV = K / 4;
    for (int i = t; i < 64 * RV; i += 256) {
        int row = i / RV, c4 = i % RV;
        float4 v = make_float4(0.f, 0.f, 0.f, 0.f);
        if (r0 + row < N) v = ((const float4*)(X + (long)(r0 + row) * K))[c4];
        *(float4*)&XL[row * XS + c4 * 4] = v;
    }
    __syncthreads();

    int ty = t >> 4, tx = t & 15;
    float acc1[4][M1], acc2[4][M2];
    #pragma unroll
    for (int i = 0; i < 4; ++i) {
        #pragma unroll
        for (int j = 0; j < M1; ++j) acc1[i][j] = 0.f;
        #pragma unroll
        for (int j = 0; j < M2; ++j) acc2[i][j] = 0.f;
    }

    const float* xb = &XL[(ty * 4) * XS];
    const float* wba = &WLa[tx * M1];
    const float* wbb = &WLb[tx * M2];
    for (int k = 0; k < K; ++k) {
        float x0 = xb[k], x1 = xb[XS + k], x2 = xb[2 * XS + k], x3 = xb[3 * XS + k];
        float wa[M1], wb2[M2];
        #pragma unroll
        for (int j = 0; j < M1; ++j) wa[j] = wba[k * C1 + j];
        #pragma unroll
        for (int j = 0; j < M2; ++j) wb2[j] = wbb[k * C2 + j];
        #pragma unroll
        for (int j = 0; j < M1; ++j) {
            acc1[0][j] = fmaf(x0, wa[j], acc1[0][j]);
            acc1[1][j] = fmaf(x1, wa[j], acc1[1][j]);
            acc1[2][j] = fmaf(x2, wa[j], acc1[2][j]);
            acc1[3][j] = fmaf(x3, wa[j], acc1[3][j]);
        }
        #pragma unroll
        for (int j = 0; j < M2; ++j) {
            acc2[0][j] = fmaf(x0, wb2[j], acc2[0][j]);
            acc2[1][j] = fmaf(x1, wb2[j], acc2[1][j]);
            acc2[2][j] = fmaf(x2, wb2[j], acc2[2][j]);
            acc2[3][j] = fmaf(x3, wb2[j], acc2[3][j]);
        }
    }

    #pragma unroll
    for (int i = 0; i < 4; ++i) {
        int row = r0 + ty * 4 + i;
        if (row < N) {
            float sc = scale ? scale[row] : 1.0f;
            #pragma unroll
            for (int j = 0; j < M1; ++j) {
                int c = tx * M1 + j;
                float v = acc1[i][j] * sc;
                if (ba) v += ba[c];
                long idx = A_SLICED ? (((long)(c >> 4) * N + row) * 16 + (c & 15))
                                    : ((long)row * C1 + c);
                outa[idx] = f2bf(v);
            }
            #pragma unroll
            for (int j = 0; j < M2; ++j) {
                int c = tx * M2 + j;
                outb[(long)row * C2 + c] = f2bf(acc2[i][j] + bb[c]);
            }
        }
    }
}

// ---------------- Aggregation, feature-sliced with XCD affinity ----------------
// hs: [NSL][N][16] bf16, dinv[src] folded. Each 16-col slice is gathered by only
// 8/NSL XCDs, so each slice's 3.2 MB working set lives in those XCDs' L2s.
// out = relu(dinv[i]*(sum + self) + bias) + skips (skips bf16, full-width F layout).

template <int NSL, int F>
__global__ __launch_bounds__(256) void aggs_kernel(const unsigned short* __restrict__ hs,
                                                   const int* __restrict__ rowptr, const int* __restrict__ col,
                                                   const float* __restrict__ dinv, const float* __restrict__ bias,
                                                   const unsigned short* __restrict__ skipA,
                                                   const unsigned short* __restrict__ skipB,
                                                   float* __restrict__ out, int N) {
    constexpr int XPS = 8 / NSL;        // XCDs per slice
    int t = threadIdx.x;
    int lane = t & 63, wv = t >> 6;
    unsigned bid = blockIdx.x;
    int xcd = bid & 7;                  // default round-robin block->XCD mapping
    int slice = xcd / XPS;
    int grp = (int)(bid >> 3) * XPS + (xcd % XPS);
    int sub = lane >> 2, fq = lane & 3; // VL=4 lanes per node, NPW=16 nodes per wave
    int i = (grp * 4 + wv) * 16 + sub;
    if (i >= N) return;

    const uint2* hv = (const uint2*)hs + (long)slice * N * 4;
    float4 a0 = make_float4(0.f, 0.f, 0.f, 0.f);
    float4 a1 = make_float4(0.f, 0.f, 0.f, 0.f);
    bfacc(hv[(long)i * 4 + fq], a0);    // self-loop term

    int p0 = rowptr[i], p1 = rowptr[i + 1];
    for (int p = p0; p < p1; p += 4) {
        int c = ((p + fq) < p1) ? col[p + fq] : 0;
        int m = min(4, p1 - p);
        if (m == 4) {
            int s0 = __shfl(c, 0, 4), s1 = __shfl(c, 1, 4);
            int s2 = __shfl(c, 2, 4), s3 = __shfl(c, 3, 4);
            uint2 u0 = hv[(long)s0 * 4 + fq];
            uint2 u1 = hv[(long)s1 * 4 + fq];
            uint2 u2 = hv[(long)s2 * 4 + fq];
            uint2 u3 = hv[(long)s3 * 4 + fq];
            bfacc(u0, a0); bfacc(u1, a1); bfacc(u2, a0); bfacc(u3, a1);
        } else {
            for (int k = 0; k < m; ++k) {
                int s = __shfl(c, k, 4);
                bfacc(hv[(long)s * 4 + fq], a1);
            }
        }
    }

    float di = dinv[i];
    float4 b4 = *(const float4*)&bias[slice * 16 + fq * 4];
    float4 v;
    v.x = fmaxf(di * (a0.x + a1.x) + b4.x, 0.f);
    v.y = fmaxf(di * (a0.y + a1.y) + b4.y, 0.f);
    v.z = fmaxf(di * (a0.z + a1.z) + b4.z, 0.f);
    v.w = fmaxf(di * (a0.w + a1.w) + b4.w, 0.f);
    long co = (long)i * F + slice * 16 + fq * 4;
    if (skipA) {
        float4 s4 = bf4(((const uint2*)skipA)[co >> 2]);
        v.x += s4.x; v.y += s4.y; v.z += s4.z; v.w += s4.w;
    }
    if (skipB) {
        float4 s4 = bf4(((const uint2*)skipB)[co >> 2]);
        v.x += s4.x; v.y += s4.y; v.z += s4.z; v.w += s4.w;
    }
    *(float4*)&out[co] = v;
}

// ---------------- launch ----------------

extern "C" void kernel_launch(void* const* d_in, const int* in_sizes, int n_in,
                              void* d_out, int out_size, void* d_ws, size_t ws_size,
                              hipStream_t stream) {
    const int N = NN;
    const float* x   = (const float*)d_in[0];
    const int*   ei  = (const int*)d_in[1];
    const int    E   = in_sizes[1] / 2;
    const int*   src = ei;
    const int*   dst = ei + E;
    const float* W1 = (const float*)d_in[2],  *b1  = (const float*)d_in[3];
    const float* W2 = (const float*)d_in[4],  *b2  = (const float*)d_in[5];
    const float* W3 = (const float*)d_in[6],  *b3  = (const float*)d_in[7];
    const float* Ws02 = (const float*)d_in[8],  *bs02 = (const float*)d_in[9];
    const float* Ws03 = (const float*)d_in[10], *bs03 = (const float*)d_in[11];
    const float* Ws13 = (const float*)d_in[12], *bs13 = (const float*)d_in[13];

    char* w = (char*)d_ws;
    size_t off = 0;
    auto alloc = [&](size_t bytes) -> void* {
        void* p = w + off;
        off += (bytes + 255) & ~(size_t)255;
        return p;
    };
    int*   bcnt     = (int*)alloc((size_t)NB * 4);
    int*   bstart   = (int*)alloc((size_t)(NB + 1) * 4);
    int*   cursors  = (int*)alloc((size_t)NB * 4);
    int*   rowptr   = (int*)alloc(((size_t)N + 1) * 4);
    float* dinv     = (float*)alloc((size_t)N * 4);
    int*   col      = (int*)alloc((size_t)E * 4);
    unsigned short* hs1 = (unsigned short*)alloc((size_t)N * 64 * 2);   // bf16 sliced [4][N][16]
    float* x1       = (float*)alloc((size_t)N * 64 * 4);
    unsigned short* s02 = (unsigned short*)alloc((size_t)N * 32 * 2);   // bf16 [N][32]
    unsigned short* s03 = (unsigned short*)alloc((size_t)N * 16 * 2);   // bf16 [N][16]
    float* x2       = (float*)alloc((size_t)N * 32 * 4);
    // aliases over dead regions
    unsigned int* packed = (unsigned int*)x1;                    // dead before agg1 writes x1
    unsigned short* hs2 = hs1;                                   // sliced [2][N][16] (first N*32 ushorts)
    unsigned short* s13 = hs1 + (size_t)N * 32;                  // bf16 [N][16] in hs1's back half
    unsigned short* hs3 = s02;                                   // [N][16] after agg2 consumed s02

    // ---- CSR build ----
    hipMemsetAsync(bcnt, 0, (size_t)NB * 4, stream);
    bcount_kernel<<<1024, 256, 0, stream>>>(dst, E, bcnt);
    bscan_kernel<<<1, NB, 0, stream>>>(bcnt, bstart, cursors, E);
    multisplit_kernel<<<(E + 4095) / 4096, 256, 0, stream>>>(src, dst, E, cursors, packed);
    bucket_fill_kernel<<<NB, 256, 0, stream>>>(packed, bstart, N, E, rowptr, col, dinv);

    int gb = (N + 63) / 64;          // 1563
    // layer 1: hs1 = dinv*(x@W1) [bf16, sliced]; {s02,s03} fused (one x pass, bf16)
    gemm_kernel<128, 64, true><<<gb, 256, 0, stream>>>(x, W1, nullptr, dinv, hs1, N);
    gemm2_kernel<128, 32, 16, false><<<gb, 256, 0, stream>>>(x, Ws02, bs02, nullptr, Ws03, bs03, s02, s03, N);
    // agg 1 -> x1 (fp32): 4 slices x 2 XCDs
    aggs_kernel<4, 64><<<8 * ((gb + 1) / 2), 256, 0, stream>>>(hs1, rowptr, col, dinv, b1, nullptr, nullptr, x1, N);
    // layer 2: {hs2 [bf16 sliced, scaled], s13 [bf16]} fused (one x1 pass)
    gemm2_kernel<64, 32, 16, true><<<gb, 256, 0, stream>>>(x1, W2, nullptr, dinv, Ws13, bs13, hs2, s13, N);
    // agg 2 -> x2 (fp32): 2 slices x 4 XCDs
    aggs_kernel<2, 32><<<8 * ((gb + 3) / 4), 256, 0, stream>>>(hs2, rowptr, col, dinv, b2, s02, nullptr, x2, N);
    // layer 3
    gemm_kernel<32, 16, false><<<gb, 256, 0, stream>>>(x2, W3, nullptr, dinv, hs3, N);
    // agg 3 -> out (fp32): 1 slice x 8 XCDs
    aggs_kernel<1, 16><<<8 * ((gb + 7) / 8), 256, 0, stream>>>(hs3, rowptr, col, dinv, b3, s03, s13, (float*)d_out, N);
}

// Round 6
// 344.684 us; speedup vs baseline: 1.2000x; 1.2000x over previous
//
#include <hip/hip_runtime.h>

#define NN 100000
#define NB 512            // buckets
#define NPB 196           // nodes per bucket: ceil(100000/512)=196; local dst fits in 8 bits

__device__ inline unsigned short f2bf(float f) {
    unsigned u = __float_as_uint(f);
    return (unsigned short)((u + 0x7FFFu + ((u >> 16) & 1u)) >> 16);
}
__device__ inline unsigned packbf(float a, float b) {
    return (unsigned)f2bf(a) | ((unsigned)f2bf(b) << 16);
}
__device__ inline float bflo(unsigned u) { return __uint_as_float(u << 16); }
__device__ inline float bfhi(unsigned u) { return __uint_as_float(u & 0xFFFF0000u); }

// accumulate 4 bf16 (packed in uint2) into float4
__device__ inline void bfacc(uint2 u, float4& a) {
    a.x += bflo(u.x); a.y += bfhi(u.x); a.z += bflo(u.y); a.w += bfhi(u.y);
}
__device__ inline float4 bf4(uint2 u) {
    return make_float4(bflo(u.x), bfhi(u.x), bflo(u.y), bfhi(u.y));
}

// ---------------- CSR build: 2-level bucket multisplit ----------------

__global__ __launch_bounds__(256) void bcount_kernel(const int* __restrict__ dst, int E, int* __restrict__ bcnt) {
    __shared__ int h[NB];
    for (int i = threadIdx.x; i < NB; i += 256) h[i] = 0;
    __syncthreads();
    for (int e = blockIdx.x * 256 + threadIdx.x; e < E; e += gridDim.x * 256)
        atomicAdd(&h[dst[e] / NPB], 1);
    __syncthreads();
    for (int i = threadIdx.x; i < NB; i += 256)
        if (h[i]) atomicAdd(&bcnt[i], h[i]);
}

__global__ __launch_bounds__(512) void bscan_kernel(const int* __restrict__ bcnt, int* __restrict__ bstart,
                                                    int* __restrict__ cursors, int E) {
    __shared__ int sh[NB];
    int t = threadIdx.x;
    int v = bcnt[t];
    sh[t] = v;
    __syncthreads();
    for (int off = 1; off < NB; off <<= 1) {
        int u = (t >= off) ? sh[t - off] : 0;
        __syncthreads();
        sh[t] += u;
        __syncthreads();
    }
    int ex = sh[t] - v;
    bstart[t] = ex;
    cursors[t] = ex;
    if (t == NB - 1) bstart[NB] = E;
}

__global__ __launch_bounds__(256) void multisplit_kernel(const int* __restrict__ src, const int* __restrict__ dst,
                                                         int E, int* __restrict__ cursors,
                                                         unsigned int* __restrict__ packed) {
    __shared__ int cnt[NB];
    __shared__ int base[NB];
    const int CH = 256 * 16;
    int t = threadIdx.x;
    for (long c0 = (long)blockIdx.x * CH; c0 < E; c0 += (long)gridDim.x * CH) {
        for (int i = t; i < NB; i += 256) cnt[i] = 0;
        __syncthreads();
        int s[16], d[16];
        #pragma unroll
        for (int k = 0; k < 16; ++k) {
            long e = c0 + k * 256 + t;
            if (e < E) {
                d[k] = dst[e];
                s[k] = src[e];
                atomicAdd(&cnt[d[k] / NPB], 1);
            } else d[k] = -1;
        }
        __syncthreads();
        for (int i = t; i < NB; i += 256)
            base[i] = cnt[i] ? atomicAdd(&cursors[i], cnt[i]) : 0;
        __syncthreads();
        #pragma unroll
        for (int k = 0; k < 16; ++k) {
            if (d[k] >= 0) {
                int b = d[k] / NPB;
                int ld = d[k] - b * NPB;
                int pos = atomicAdd(&base[b], 1);
                packed[pos] = ((unsigned int)s[k] << 8) | (unsigned int)ld;
            }
        }
        __syncthreads();
    }
}

__global__ __launch_bounds__(256) void bucket_fill_kernel(const unsigned int* __restrict__ packed,
                                                          const int* __restrict__ bstart, int N, int E,
                                                          int* __restrict__ rowptr, int* __restrict__ col,
                                                          float* __restrict__ dinv) {
    int b = blockIdx.x, t = threadIdx.x;
    int e0 = bstart[b], e1 = bstart[b + 1];
    __shared__ int hist[256];
    __shared__ int sh[256];
    __shared__ int cur[256];
    hist[t] = 0;
    __syncthreads();
    for (int e = e0 + t; e < e1; e += 256)
        atomicAdd(&hist[packed[e] & 255u], 1);
    __syncthreads();
    int v = hist[t];
    sh[t] = v;
    __syncthreads();
    for (int off = 1; off < 256; off <<= 1) {
        int u = (t >= off) ? sh[t - off] : 0;
        __syncthreads();
        sh[t] += u;
        __syncthreads();
    }
    int ex = sh[t] - v;
    int node = b * NPB + t;
    if (t < NPB && node < N) {
        rowptr[node] = e0 + ex;
        dinv[node] = rsqrtf(1.0f + (float)v);
    }
    cur[t] = e0 + ex;
    __syncthreads();
    for (int e = e0 + t; e < e1; e += 256) {
        unsigned int p = packed[e];
        int pos = atomicAdd(&cur[p & 255u], 1);
        col[pos] = (int)(p >> 8);
    }
    if (b == 0 && t == 0) rowptr[N] = E;
}

// ---------------- gemm3: one x pass -> hs1 (64, scaled, bf16), s02 (32, bias, bf16), s03 (16, bias, bf16) ----
// Weights staged in LDS as bf16 k-pair packed uints; X staged fp32 (XS=K+6 -> 4-way max bank conflict).

__global__ __launch_bounds__(256) void gemm3_kernel(const float* __restrict__ X,
        const float* __restrict__ Wa, const float* __restrict__ Wb, const float* __restrict__ bb,
        const float* __restrict__ Wc, const float* __restrict__ bc, const float* __restrict__ scale,
        unsigned short* __restrict__ oa, unsigned short* __restrict__ ob, unsigned short* __restrict__ oc, int N) {
    constexpr int K = 128, XS = K + 6;
    __shared__ float XL[64 * XS];
    __shared__ unsigned WPa[(K / 2) * 64];
    __shared__ unsigned WPb[(K / 2) * 32];
    __shared__ unsigned WPc[(K / 2) * 16];
    int t = threadIdx.x;
    int r0 = blockIdx.x * 64;

    for (int i = t; i < (K / 2) * 64; i += 256) {
        int kp = i >> 6, c = i & 63;
        WPa[i] = packbf(Wa[(2 * kp) * 64 + c], Wa[(2 * kp + 1) * 64 + c]);
    }
    for (int i = t; i < (K / 2) * 32; i += 256) {
        int kp = i >> 5, c = i & 31;
        WPb[i] = packbf(Wb[(2 * kp) * 32 + c], Wb[(2 * kp + 1) * 32 + c]);
    }
    for (int i = t; i < (K / 2) * 16; i += 256) {
        int kp = i >> 4, c = i & 15;
        WPc[i] = packbf(Wc[(2 * kp) * 16 + c], Wc[(2 * kp + 1) * 16 + c]);
    }
    for (int i = t; i < 64 * (K / 2); i += 256) {
        int row = i / (K / 2), c2 = i % (K / 2);
        float2 v = make_float2(0.f, 0.f);
        if (r0 + row < N) v = ((const float2*)(X + (size_t)(r0 + row) * K))[c2];
        *(float2*)&XL[row * XS + c2 * 2] = v;
    }
    __syncthreads();

    int ty = t >> 4, tx = t & 15;
    float a1[4][4] = {}, a2[4][2] = {}, a3[4] = {0.f, 0.f, 0.f, 0.f};
    const float* xb = &XL[(ty * 4) * XS];

    for (int kp = 0; kp < K / 2; ++kp) {
        float2 x0 = *(const float2*)&xb[kp * 2];
        float2 x1 = *(const float2*)&xb[XS + kp * 2];
        float2 x2 = *(const float2*)&xb[2 * XS + kp * 2];
        float2 x3 = *(const float2*)&xb[3 * XS + kp * 2];
        uint4 ua = *(const uint4*)&WPa[kp * 64 + tx * 4];
        uint2 ub = *(const uint2*)&WPb[kp * 32 + tx * 2];
        unsigned uc = WPc[kp * 16 + tx];
        #pragma unroll
        for (int j = 0; j < 4; ++j) {
            unsigned u = (&ua.x)[j];
            float wl = bflo(u), wh = bfhi(u);
            a1[0][j] = fmaf(x0.y, wh, fmaf(x0.x, wl, a1[0][j]));
            a1[1][j] = fmaf(x1.y, wh, fmaf(x1.x, wl, a1[1][j]));
            a1[2][j] = fmaf(x2.y, wh, fmaf(x2.x, wl, a1[2][j]));
            a1[3][j] = fmaf(x3.y, wh, fmaf(x3.x, wl, a1[3][j]));
        }
        #pragma unroll
        for (int j = 0; j < 2; ++j) {
            unsigned u = (&ub.x)[j];
            float wl = bflo(u), wh = bfhi(u);
            a2[0][j] = fmaf(x0.y, wh, fmaf(x0.x, wl, a2[0][j]));
            a2[1][j] = fmaf(x1.y, wh, fmaf(x1.x, wl, a2[1][j]));
            a2[2][j] = fmaf(x2.y, wh, fmaf(x2.x, wl, a2[2][j]));
            a2[3][j] = fmaf(x3.y, wh, fmaf(x3.x, wl, a2[3][j]));
        }
        {
            float wl = bflo(uc), wh = bfhi(uc);
            a3[0] = fmaf(x0.y, wh, fmaf(x0.x, wl, a3[0]));
            a3[1] = fmaf(x1.y, wh, fmaf(x1.x, wl, a3[1]));
            a3[2] = fmaf(x2.y, wh, fmaf(x2.x, wl, a3[2]));
            a3[3] = fmaf(x3.y, wh, fmaf(x3.x, wl, a3[3]));
        }
    }

    float2 bb2 = *(const float2*)&bb[tx * 2];
    float bc1 = bc[tx];
    #pragma unroll
    for (int i = 0; i < 4; ++i) {
        int row = r0 + ty * 4 + i;
        if (row < N) {
            float sc = scale[row];
            uint2 o;
            o.x = packbf(a1[i][0] * sc, a1[i][1] * sc);
            o.y = packbf(a1[i][2] * sc, a1[i][3] * sc);
            ((uint2*)(oa + (size_t)row * 64))[tx] = o;
            ((unsigned*)(ob + (size_t)row * 32))[tx] = packbf(a2[i][0] + bb2.x, a2[i][1] + bb2.y);
            oc[(size_t)row * 16 + tx] = f2bf(a3[i] + bc1);
        }
    }
}

// ---------------- gemm2b: bf16 X input, two bf16 outputs (a: scaled; b: bias) ----------------

template <int K, int C1, int C2>
__global__ __launch_bounds__(256) void gemm2b_kernel(const unsigned short* __restrict__ X,
        const float* __restrict__ Wa, const float* __restrict__ scale,
        const float* __restrict__ Wb, const float* __restrict__ bb,
        unsigned short* __restrict__ oa, unsigned short* __restrict__ ob, int N) {
    constexpr int M1 = C1 / 16, M2 = C2 / 16;
    constexpr int XS = K + 6;
    __shared__ float XL[64 * XS];
    __shared__ float WLa[K * C1];
    __shared__ float WLb[K * C2];
    int t = threadIdx.x;
    int r0 = blockIdx.x * 64;

    for (int i = t; i < K * C1 / 4; i += 256) ((float4*)WLa)[i] = ((const float4*)Wa)[i];
    for (int i = t; i < K * C2 / 4; i += 256) ((float4*)WLb)[i] = ((const float4*)Wb)[i];
    for (int i = t; i < 64 * (K / 4); i += 256) {
        int row = i / (K / 4), g = i % (K / 4);
        uint2 u = make_uint2(0u, 0u);
        if (r0 + row < N) u = ((const uint2*)(X + (size_t)(r0 + row) * K))[g];
        float* p = &XL[row * XS + g * 4];
        *(float2*)p = make_float2(bflo(u.x), bfhi(u.x));
        *(float2*)(p + 2) = make_float2(bflo(u.y), bfhi(u.y));
    }
    __syncthreads();

    int ty = t >> 4, tx = t & 15;
    float acc1[4][M1] = {}, acc2[4][M2] = {};
    const float* xb = &XL[(ty * 4) * XS];
    const float* wba = &WLa[tx * M1];
    const float* wbb = &WLb[tx * M2];
    for (int k = 0; k < K; ++k) {
        float x0 = xb[k], x1 = xb[XS + k], x2 = xb[2 * XS + k], x3 = xb[3 * XS + k];
        float wa[M1], wb2[M2];
        #pragma unroll
        for (int j = 0; j < M1; ++j) wa[j] = wba[k * C1 + j];
        #pragma unroll
        for (int j = 0; j < M2; ++j) wb2[j] = wbb[k * C2 + j];
        #pragma unroll
        for (int j = 0; j < M1; ++j) {
            acc1[0][j] = fmaf(x0, wa[j], acc1[0][j]);
            acc1[1][j] = fmaf(x1, wa[j], acc1[1][j]);
            acc1[2][j] = fmaf(x2, wa[j], acc1[2][j]);
            acc1[3][j] = fmaf(x3, wa[j], acc1[3][j]);
        }
        #pragma unroll
        for (int j = 0; j < M2; ++j) {
            acc2[0][j] = fmaf(x0, wb2[j], acc2[0][j]);
            acc2[1][j] = fmaf(x1, wb2[j], acc2[1][j]);
            acc2[2][j] = fmaf(x2, wb2[j], acc2[2][j]);
            acc2[3][j] = fmaf(x3, wb2[j], acc2[3][j]);
        }
    }

    #pragma unroll
    for (int i = 0; i < 4; ++i) {
        int row = r0 + ty * 4 + i;
        if (row < N) {
            float sc = scale[row];
            ((unsigned*)(oa + (size_t)row * C1))[tx] = packbf(acc1[i][0] * sc, acc1[i][1] * sc);
            ob[(size_t)row * C2 + tx] = f2bf(acc2[i][0] + bb[tx]);
        }
    }
}

// ---------------- gemm_l3: bf16 X [N][32] -> hs3 [N][16] bf16, scaled ----------------

__global__ __launch_bounds__(256) void gemm_l3_kernel(const unsigned short* __restrict__ X,
        const float* __restrict__ W, const float* __restrict__ scale,
        unsigned short* __restrict__ out, int N) {
    constexpr int K = 32, C = 16, XS = K + 6;
    __shared__ float XL[64 * XS];
    __shared__ float WL[K * C];
    int t = threadIdx.x;
    int r0 = blockIdx.x * 64;

    for (int i = t; i < K * C / 4; i += 256) ((float4*)WL)[i] = ((const float4*)W)[i];
    for (int i = t; i < 64 * (K / 4); i += 256) {
        int row = i / (K / 4), g = i % (K / 4);
        uint2 u = make_uint2(0u, 0u);
        if (r0 + row < N) u = ((const uint2*)(X + (size_t)(r0 + row) * K))[g];
        float* p = &XL[row * XS + g * 4];
        *(float2*)p = make_float2(bflo(u.x), bfhi(u.x));
        *(float2*)(p + 2) = make_float2(bflo(u.y), bfhi(u.y));
    }
    __syncthreads();

    int ty = t >> 4, tx = t & 15;
    float acc[4] = {0.f, 0.f, 0.f, 0.f};
    const float* xb = &XL[(ty * 4) * XS];
    for (int k = 0; k < K; ++k) {
        float wv = WL[k * C + tx];
        acc[0] = fmaf(xb[k], wv, acc[0]);
        acc[1] = fmaf(xb[XS + k], wv, acc[1]);
        acc[2] = fmaf(xb[2 * XS + k], wv, acc[2]);
        acc[3] = fmaf(xb[3 * XS + k], wv, acc[3]);
    }
    #pragma unroll
    for (int i = 0; i < 4; ++i) {
        int row = r0 + ty * 4 + i;
        if (row < N) out[(size_t)row * C + tx] = f2bf(acc[i] * scale[row]);
    }
}

// ---------------- Aggregation ----------------
// out = relu(dinv[i]*(sum_nbr hs[src] + hs[i]) + b) + skips; hs bf16 (dinv[src] folded).
// Lane loads uint2 = 4 bf16; VL=F/4 lanes/row; 8-deep load pipeline, 4 acc chains.
// OBF: write bf16 (packed uint2), else fp32 float4. Skips are bf16.

template <int F, bool OBF>
__global__ __launch_bounds__(256) void agg_kernel(const unsigned short* __restrict__ hs,
        const int* __restrict__ rowptr, const int* __restrict__ col,
        const float* __restrict__ dinv, const float* __restrict__ bias,
        const unsigned short* __restrict__ skipA, const unsigned short* __restrict__ skipB,
        void* __restrict__ outv, int N) {
    constexpr int VL = F / 4;           // lanes per row
    constexpr int NPW = 64 / VL;        // nodes per wave
    int t = threadIdx.x;
    int lane = t & 63, wv = t >> 6;
    int sub = lane / VL, fq = lane % VL;
    int i = (blockIdx.x * 4 + wv) * NPW + sub;
    if (i >= N) return;

    const uint2* hv = (const uint2*)hs;
    float4 a0 = make_float4(0.f, 0.f, 0.f, 0.f);
    float4 a1 = make_float4(0.f, 0.f, 0.f, 0.f);
    float4 a2 = make_float4(0.f, 0.f, 0.f, 0.f);
    float4 a3 = make_float4(0.f, 0.f, 0.f, 0.f);
    bfacc(hv[(size_t)i * VL + fq], a0);   // self-loop term

    int p0 = rowptr[i], p1 = rowptr[i + 1];
    for (int p = p0; p < p1; p += VL) {
        int c = ((p + fq) < p1) ? col[p + fq] : 0;
        int m = min(VL, p1 - p);
        int k = 0;
        for (; k + 8 <= m; k += 8) {
            int s0 = __shfl(c, k + 0, VL), s1 = __shfl(c, k + 1, VL);
            int s2 = __shfl(c, k + 2, VL), s3 = __shfl(c, k + 3, VL);
            int s4 = __shfl(c, k + 4, VL), s5 = __shfl(c, k + 5, VL);
            int s6 = __shfl(c, k + 6, VL), s7 = __shfl(c, k + 7, VL);
            uint2 u0 = hv[(size_t)s0 * VL + fq], u1 = hv[(size_t)s1 * VL + fq];
            uint2 u2 = hv[(size_t)s2 * VL + fq], u3 = hv[(size_t)s3 * VL + fq];
            uint2 u4 = hv[(size_t)s4 * VL + fq], u5 = hv[(size_t)s5 * VL + fq];
            uint2 u6 = hv[(size_t)s6 * VL + fq], u7 = hv[(size_t)s7 * VL + fq];
            bfacc(u0, a0); bfacc(u1, a1); bfacc(u2, a2); bfacc(u3, a3);
            bfacc(u4, a0); bfacc(u5, a1); bfacc(u6, a2); bfacc(u7, a3);
        }
        for (; k + 4 <= m; k += 4) {
            int s0 = __shfl(c, k + 0, VL), s1 = __shfl(c, k + 1, VL);
            int s2 = __shfl(c, k + 2, VL), s3 = __shfl(c, k + 3, VL);
            uint2 u0 = hv[(size_t)s0 * VL + fq], u1 = hv[(size_t)s1 * VL + fq];
            uint2 u2 = hv[(size_t)s2 * VL + fq], u3 = hv[(size_t)s3 * VL + fq];
            bfacc(u0, a0); bfacc(u1, a1); bfacc(u2, a2); bfacc(u3, a3);
        }
        for (; k < m; ++k) {
            int s = __shfl(c, k, VL);
            bfacc(hv[(size_t)s * VL + fq], a1);
        }
    }

    float di = dinv[i];
    float4 b4 = *(const float4*)&bias[fq * 4];
    float4 v;
    v.x = fmaxf(di * ((a0.x + a1.x) + (a2.x + a3.x)) + b4.x, 0.f);
    v.y = fmaxf(di * ((a0.y + a1.y) + (a2.y + a3.y)) + b4.y, 0.f);
    v.z = fmaxf(di * ((a0.z + a1.z) + (a2.z + a3.z)) + b4.z, 0.f);
    v.w = fmaxf(di * ((a0.w + a1.w) + (a2.w + a3.w)) + b4.w, 0.f);
    size_t vo = (size_t)i * VL + fq;
    if (skipA) {
        float4 s4 = bf4(((const uint2*)skipA)[vo]);
        v.x += s4.x; v.y += s4.y; v.z += s4.z; v.w += s4.w;
    }
    if (skipB) {
        float4 s4 = bf4(((const uint2*)skipB)[vo]);
        v.x += s4.x; v.y += s4.y; v.z += s4.z; v.w += s4.w;
    }
    if (OBF) {
        uint2 o;
        o.x = packbf(v.x, v.y);
        o.y = packbf(v.z, v.w);
        ((uint2*)outv)[vo] = o;
    } else {
        ((float4*)outv)[vo] = v;
    }
}

// ---------------- launch ----------------

extern "C" void kernel_launch(void* const* d_in, const int* in_sizes, int n_in,
                              void* d_out, int out_size, void* d_ws, size_t ws_size,
                              hipStream_t stream) {
    const int N = NN;
    const float* x   = (const float*)d_in[0];
    const int*   ei  = (const int*)d_in[1];
    const int    E   = in_sizes[1] / 2;
    const int*   src = ei;
    const int*   dst = ei + E;
    const float* W1 = (const float*)d_in[2],  *b1  = (const float*)d_in[3];
    const float* W2 = (const float*)d_in[4],  *b2  = (const float*)d_in[5];
    const float* W3 = (const float*)d_in[6],  *b3  = (const float*)d_in[7];
    const float* Ws02 = (const float*)d_in[8],  *bs02 = (const float*)d_in[9];
    const float* Ws03 = (const float*)d_in[10], *bs03 = (const float*)d_in[11];
    const float* Ws13 = (const float*)d_in[12], *bs13 = (const float*)d_in[13];

    char* w = (char*)d_ws;
    size_t off = 0;
    auto alloc = [&](size_t bytes) -> void* {
        void* p = w + off;
        off += (bytes + 255) & ~(size_t)255;
        return p;
    };
    int*   bcnt     = (int*)alloc((size_t)NB * 4);
    int*   bstart   = (int*)alloc((size_t)(NB + 1) * 4);
    int*   cursors  = (int*)alloc((size_t)NB * 4);
    int*   rowptr   = (int*)alloc(((size_t)N + 1) * 4);
    float* dinv     = (float*)alloc((size_t)N * 4);
    int*   col      = (int*)alloc((size_t)E * 4);
    unsigned short* hs1 = (unsigned short*)alloc((size_t)N * 64 * 2);   // bf16 [N][64]
    unsigned short* x1  = (unsigned short*)alloc((size_t)N * 64 * 2);   // bf16 [N][64]
    unsigned short* s02 = (unsigned short*)alloc((size_t)N * 32 * 2);   // bf16 [N][32]
    unsigned short* s03 = (unsigned short*)alloc((size_t)N * 16 * 2);   // bf16 [N][16]
    unsigned short* x2  = (unsigned short*)alloc((size_t)N * 32 * 2);   // bf16 [N][32]
    // aliases over dead regions
    unsigned int* packed = (unsigned int*)x1;           // E*4 = 12.8MB == N*64*2; dead before agg1 writes x1
    unsigned short* hs2 = hs1;                          // [N][32] in hs1's first half (hs1 dead after agg1)
    unsigned short* s13 = hs1 + (size_t)N * 32;         // [N][16] in hs1's back half
    unsigned short* hs3 = s02;                          // [N][16] (s02 dead after agg2)

    // ---- CSR build ----
    hipMemsetAsync(bcnt, 0, (size_t)NB * 4, stream);
    bcount_kernel<<<1024, 256, 0, stream>>>(dst, E, bcnt);
    bscan_kernel<<<1, NB, 0, stream>>>(bcnt, bstart, cursors, E);
    multisplit_kernel<<<(E + 4095) / 4096, 256, 0, stream>>>(src, dst, E, cursors, packed);
    bucket_fill_kernel<<<NB, 256, 0, stream>>>(packed, bstart, N, E, rowptr, col, dinv);

    int gb = (N + 63) / 64;
    // layer 1: one x pass -> hs1 (scaled bf16), s02, s03
    gemm3_kernel<<<gb, 256, 0, stream>>>(x, W1, Ws02, bs02, Ws03, bs03, dinv, hs1, s02, s03, N);
    // agg 1 -> x1 (bf16)
    agg_kernel<64, true><<<(N + 15) / 16, 256, 0, stream>>>(hs1, rowptr, col, dinv, b1, nullptr, nullptr, x1, N);
    // layer 2: one x1 pass -> hs2 (scaled bf16), s13 (bf16)
    gemm2b_kernel<64, 32, 16><<<gb, 256, 0, stream>>>(x1, W2, dinv, Ws13, bs13, hs2, s13, N);
    // agg 2 -> x2 (bf16), skip s02
    agg_kernel<32, true><<<(N + 31) / 32, 256, 0, stream>>>(hs2, rowptr, col, dinv, b2, s02, nullptr, x2, N);
    // layer 3
    gemm_l3_kernel<<<gb, 256, 0, stream>>>(x2, W3, dinv, hs3, N);
    // agg 3 -> out (fp32), skips s03 + s13
    agg_kernel<16, false><<<(N + 63) / 64, 256, 0, stream>>>(hs3, rowptr, col, dinv, b3, s03, s13, (float*)d_out, N);
}

// Round 7
// 338.639 us; speedup vs baseline: 1.2214x; 1.0179x over previous
//
#include <hip/hip_runtime.h>

#define NN 100000
#define NB 512            // buckets
#define NPB 196           // nodes per bucket: ceil(100000/512)=196; local dst fits in 8 bits

__device__ inline unsigned short f2bf(float f) {
    unsigned u = __float_as_uint(f);
    return (unsigned short)((u + 0x7FFFu + ((u >> 16) & 1u)) >> 16);
}
__device__ inline unsigned packbf(float a, float b) {
    return (unsigned)f2bf(a) | ((unsigned)f2bf(b) << 16);
}
__device__ inline float bflo(unsigned u) { return __uint_as_float(u << 16); }
__device__ inline float bfhi(unsigned u) { return __uint_as_float(u & 0xFFFF0000u); }

// accumulate 4 bf16 (packed in uint2) into float4
__device__ inline void bfacc(uint2 u, float4& a) {
    a.x += bflo(u.x); a.y += bfhi(u.x); a.z += bflo(u.y); a.w += bfhi(u.y);
}
__device__ inline float4 bf4(uint2 u) {
    return make_float4(bflo(u.x), bfhi(u.x), bflo(u.y), bfhi(u.y));
}

// ---------------- CSR build: 2-level bucket multisplit ----------------

__global__ __launch_bounds__(256) void bcount_kernel(const int* __restrict__ dst, int E, int* __restrict__ bcnt) {
    __shared__ int h[NB];
    for (int i = threadIdx.x; i < NB; i += 256) h[i] = 0;
    __syncthreads();
    for (int e = blockIdx.x * 256 + threadIdx.x; e < E; e += gridDim.x * 256)
        atomicAdd(&h[dst[e] / NPB], 1);
    __syncthreads();
    for (int i = threadIdx.x; i < NB; i += 256)
        if (h[i]) atomicAdd(&bcnt[i], h[i]);
}

__global__ __launch_bounds__(512) void bscan_kernel(const int* __restrict__ bcnt, int* __restrict__ bstart,
                                                    int* __restrict__ cursors, int E) {
    __shared__ int sh[NB];
    int t = threadIdx.x;
    int v = bcnt[t];
    sh[t] = v;
    __syncthreads();
    for (int off = 1; off < NB; off <<= 1) {
        int u = (t >= off) ? sh[t - off] : 0;
        __syncthreads();
        sh[t] += u;
        __syncthreads();
    }
    int ex = sh[t] - v;
    bstart[t] = ex;
    cursors[t] = ex;
    if (t == NB - 1) bstart[NB] = E;
}

__global__ __launch_bounds__(256) void multisplit_kernel(const int* __restrict__ src, const int* __restrict__ dst,
                                                         int E, int* __restrict__ cursors,
                                                         unsigned int* __restrict__ packed) {
    __shared__ int cnt[NB];
    __shared__ int base[NB];
    const int CH = 256 * 16;
    int t = threadIdx.x;
    for (long c0 = (long)blockIdx.x * CH; c0 < E; c0 += (long)gridDim.x * CH) {
        for (int i = t; i < NB; i += 256) cnt[i] = 0;
        __syncthreads();
        int s[16], d[16];
        #pragma unroll
        for (int k = 0; k < 16; ++k) {
            long e = c0 + k * 256 + t;
            if (e < E) {
                d[k] = dst[e];
                s[k] = src[e];
                atomicAdd(&cnt[d[k] / NPB], 1);
            } else d[k] = -1;
        }
        __syncthreads();
        for (int i = t; i < NB; i += 256)
            base[i] = cnt[i] ? atomicAdd(&cursors[i], cnt[i]) : 0;
        __syncthreads();
        #pragma unroll
        for (int k = 0; k < 16; ++k) {
            if (d[k] >= 0) {
                int b = d[k] / NPB;
                int ld = d[k] - b * NPB;
                int pos = atomicAdd(&base[b], 1);
                packed[pos] = ((unsigned int)s[k] << 8) | (unsigned int)ld;
            }
        }
        __syncthreads();
    }
}

__global__ __launch_bounds__(256) void bucket_fill_kernel(const unsigned int* __restrict__ packed,
                                                          const int* __restrict__ bstart, int N, int E,
                                                          int* __restrict__ rowptr, int* __restrict__ col,
                                                          float* __restrict__ dinv) {
    int b = blockIdx.x, t = threadIdx.x;
    int e0 = bstart[b], e1 = bstart[b + 1];
    __shared__ int hist[256];
    __shared__ int sh[256];
    __shared__ int cur[256];
    hist[t] = 0;
    __syncthreads();
    for (int e = e0 + t; e < e1; e += 256)
        atomicAdd(&hist[packed[e] & 255u], 1);
    __syncthreads();
    int v = hist[t];
    sh[t] = v;
    __syncthreads();
    for (int off = 1; off < 256; off <<= 1) {
        int u = (t >= off) ? sh[t - off] : 0;
        __syncthreads();
        sh[t] += u;
        __syncthreads();
    }
    int ex = sh[t] - v;
    int node = b * NPB + t;
    if (t < NPB && node < N) {
        rowptr[node] = e0 + ex;
        dinv[node] = rsqrtf(1.0f + (float)v);
    }
    cur[t] = e0 + ex;
    __syncthreads();
    for (int e = e0 + t; e < e1; e += 256) {
        unsigned int p = packed[e];
        int pos = atomicAdd(&cur[p & 255u], 1);
        col[pos] = (int)(p >> 8);
    }
    if (b == 0 && t == 0) rowptr[N] = E;
}

// ---------------- gemm3: one x pass -> hs1 (64, scaled, bf16), s02 (32, bias, bf16), s03 (16, bias, bf16) ----
// X AND W staged in LDS as bf16 k-pair packed uints: LDS = 16.6 + 28 KB = 44.6 KB -> 3 blocks/CU.

__global__ __launch_bounds__(256) void gemm3_kernel(const float* __restrict__ X,
        const float* __restrict__ Wa, const float* __restrict__ Wb, const float* __restrict__ bb,
        const float* __restrict__ Wc, const float* __restrict__ bc, const float* __restrict__ scale,
        unsigned short* __restrict__ oa, unsigned short* __restrict__ ob, unsigned short* __restrict__ oc, int N) {
    constexpr int K = 128, KP = K / 2, XSP = KP + 1;   // 64 k-pairs, stride 65 uints
    __shared__ unsigned XP[64 * XSP];                   // 16.6 KB
    __shared__ unsigned WPa[KP * 64];                   // 16 KB
    __shared__ unsigned WPb[KP * 32];                   // 8 KB
    __shared__ unsigned WPc[KP * 16];                   // 4 KB
    int t = threadIdx.x;
    int r0 = blockIdx.x * 64;

    for (int i = t; i < KP * 64; i += 256) {
        int kp = i >> 6, c = i & 63;
        WPa[i] = packbf(Wa[(2 * kp) * 64 + c], Wa[(2 * kp + 1) * 64 + c]);
    }
    for (int i = t; i < KP * 32; i += 256) {
        int kp = i >> 5, c = i & 31;
        WPb[i] = packbf(Wb[(2 * kp) * 32 + c], Wb[(2 * kp + 1) * 32 + c]);
    }
    for (int i = t; i < KP * 16; i += 256) {
        int kp = i >> 4, c = i & 15;
        WPc[i] = packbf(Wc[(2 * kp) * 16 + c], Wc[(2 * kp + 1) * 16 + c]);
    }
    for (int i = t; i < 64 * KP; i += 256) {
        int row = i / KP, c2 = i % KP;
        float2 v = make_float2(0.f, 0.f);
        if (r0 + row < N) v = ((const float2*)(X + (size_t)(r0 + row) * K))[c2];
        XP[row * XSP + c2] = packbf(v.x, v.y);
    }
    __syncthreads();

    int ty = t >> 4, tx = t & 15;
    float a1[4][4] = {}, a2[4][2] = {}, a3[4] = {0.f, 0.f, 0.f, 0.f};
    const unsigned* xb = &XP[(ty * 4) * XSP];

    for (int kp = 0; kp < KP; ++kp) {
        unsigned px0 = xb[kp], px1 = xb[XSP + kp], px2 = xb[2 * XSP + kp], px3 = xb[3 * XSP + kp];
        float x0l = bflo(px0), x0h = bfhi(px0);
        float x1l = bflo(px1), x1h = bfhi(px1);
        float x2l = bflo(px2), x2h = bfhi(px2);
        float x3l = bflo(px3), x3h = bfhi(px3);
        uint4 ua = *(const uint4*)&WPa[kp * 64 + tx * 4];
        uint2 ub = *(const uint2*)&WPb[kp * 32 + tx * 2];
        unsigned uc = WPc[kp * 16 + tx];
        #pragma unroll
        for (int j = 0; j < 4; ++j) {
            unsigned u = (&ua.x)[j];
            float wl = bflo(u), wh = bfhi(u);
            a1[0][j] = fmaf(x0h, wh, fmaf(x0l, wl, a1[0][j]));
            a1[1][j] = fmaf(x1h, wh, fmaf(x1l, wl, a1[1][j]));
            a1[2][j] = fmaf(x2h, wh, fmaf(x2l, wl, a1[2][j]));
            a1[3][j] = fmaf(x3h, wh, fmaf(x3l, wl, a1[3][j]));
        }
        #pragma unroll
        for (int j = 0; j < 2; ++j) {
            unsigned u = (&ub.x)[j];
            float wl = bflo(u), wh = bfhi(u);
            a2[0][j] = fmaf(x0h, wh, fmaf(x0l, wl, a2[0][j]));
            a2[1][j] = fmaf(x1h, wh, fmaf(x1l, wl, a2[1][j]));
            a2[2][j] = fmaf(x2h, wh, fmaf(x2l, wl, a2[2][j]));
            a2[3][j] = fmaf(x3h, wh, fmaf(x3l, wl, a2[3][j]));
        }
        {
            float wl = bflo(uc), wh = bfhi(uc);
            a3[0] = fmaf(x0h, wh, fmaf(x0l, wl, a3[0]));
            a3[1] = fmaf(x1h, wh, fmaf(x1l, wl, a3[1]));
            a3[2] = fmaf(x2h, wh, fmaf(x2l, wl, a3[2]));
            a3[3] = fmaf(x3h, wh, fmaf(x3l, wl, a3[3]));
        }
    }

    float2 bb2 = *(const float2*)&bb[tx * 2];
    float bc1 = bc[tx];
    #pragma unroll
    for (int i = 0; i < 4; ++i) {
        int row = r0 + ty * 4 + i;
        if (row < N) {
            float sc = scale[row];
            uint2 o;
            o.x = packbf(a1[i][0] * sc, a1[i][1] * sc);
            o.y = packbf(a1[i][2] * sc, a1[i][3] * sc);
            ((uint2*)(oa + (size_t)row * 64))[tx] = o;
            ((unsigned*)(ob + (size_t)row * 32))[tx] = packbf(a2[i][0] + bb2.x, a2[i][1] + bb2.y);
            oc[(size_t)row * 16 + tx] = f2bf(a3[i] + bc1);
        }
    }
}

// ---------------- gemm2b: bf16 X input, two bf16 outputs (a: scaled; b: bias) ----------------

template <int K, int C1, int C2>
__global__ __launch_bounds__(256) void gemm2b_kernel(const unsigned short* __restrict__ X,
        const float* __restrict__ Wa, const float* __restrict__ scale,
        const float* __restrict__ Wb, const float* __restrict__ bb,
        unsigned short* __restrict__ oa, unsigned short* __restrict__ ob, int N) {
    constexpr int M1 = C1 / 16, M2 = C2 / 16;
    constexpr int XS = K + 6;
    __shared__ float XL[64 * XS];
    __shared__ float WLa[K * C1];
    __shared__ float WLb[K * C2];
    int t = threadIdx.x;
    int r0 = blockIdx.x * 64;

    for (int i = t; i < K * C1 / 4; i += 256) ((float4*)WLa)[i] = ((const float4*)Wa)[i];
    for (int i = t; i < K * C2 / 4; i += 256) ((float4*)WLb)[i] = ((const float4*)Wb)[i];
    for (int i = t; i < 64 * (K / 4); i += 256) {
        int row = i / (K / 4), g = i % (K / 4);
        uint2 u = make_uint2(0u, 0u);
        if (r0 + row < N) u = ((const uint2*)(X + (size_t)(r0 + row) * K))[g];
        float* p = &XL[row * XS + g * 4];
        *(float2*)p = make_float2(bflo(u.x), bfhi(u.x));
        *(float2*)(p + 2) = make_float2(bflo(u.y), bfhi(u.y));
    }
    __syncthreads();

    int ty = t >> 4, tx = t & 15;
    float acc1[4][M1] = {}, acc2[4][M2] = {};
    const float* xb = &XL[(ty * 4) * XS];
    const float* wba = &WLa[tx * M1];
    const float* wbb = &WLb[tx * M2];
    for (int k = 0; k < K; ++k) {
        float x0 = xb[k], x1 = xb[XS + k], x2 = xb[2 * XS + k], x3 = xb[3 * XS + k];
        float wa[M1], wb2[M2];
        #pragma unroll
        for (int j = 0; j < M1; ++j) wa[j] = wba[k * C1 + j];
        #pragma unroll
        for (int j = 0; j < M2; ++j) wb2[j] = wbb[k * C2 + j];
        #pragma unroll
        for (int j = 0; j < M1; ++j) {
            acc1[0][j] = fmaf(x0, wa[j], acc1[0][j]);
            acc1[1][j] = fmaf(x1, wa[j], acc1[1][j]);
            acc1[2][j] = fmaf(x2, wa[j], acc1[2][j]);
            acc1[3][j] = fmaf(x3, wa[j], acc1[3][j]);
        }
        #pragma unroll
        for (int j = 0; j < M2; ++j) {
            acc2[0][j] = fmaf(x0, wb2[j], acc2[0][j]);
            acc2[1][j] = fmaf(x1, wb2[j], acc2[1][j]);
            acc2[2][j] = fmaf(x2, wb2[j], acc2[2][j]);
            acc2[3][j] = fmaf(x3, wb2[j], acc2[3][j]);
        }
    }

    #pragma unroll
    for (int i = 0; i < 4; ++i) {
        int row = r0 + ty * 4 + i;
        if (row < N) {
            float sc = scale[row];
            ((unsigned*)(oa + (size_t)row * C1))[tx] = packbf(acc1[i][0] * sc, acc1[i][1] * sc);
            ob[(size_t)row * C2 + tx] = f2bf(acc2[i][0] + bb[tx]);
        }
    }
}

// ---------------- gemm_l3: bf16 X [N][32] -> hs3 [N][16] bf16, scaled ----------------

__global__ __launch_bounds__(256) void gemm_l3_kernel(const unsigned short* __restrict__ X,
        const float* __restrict__ W, const float* __restrict__ scale,
        unsigned short* __restrict__ out, int N) {
    constexpr int K = 32, C = 16, XS = K + 6;
    __shared__ float XL[64 * XS];
    __shared__ float WL[K * C];
    int t = threadIdx.x;
    int r0 = blockIdx.x * 64;

    for (int i = t; i < K * C / 4; i += 256) ((float4*)WL)[i] = ((const float4*)W)[i];
    for (int i = t; i < 64 * (K / 4); i += 256) {
        int row = i / (K / 4), g = i % (K / 4);
        uint2 u = make_uint2(0u, 0u);
        if (r0 + row < N) u = ((const uint2*)(X + (size_t)(r0 + row) * K))[g];
        float* p = &XL[row * XS + g * 4];
        *(float2*)p = make_float2(bflo(u.x), bfhi(u.x));
        *(float2*)(p + 2) = make_float2(bflo(u.y), bfhi(u.y));
    }
    __syncthreads();

    int ty = t >> 4, tx = t & 15;
    float acc[4] = {0.f, 0.f, 0.f, 0.f};
    const float* xb = &XL[(ty * 4) * XS];
    for (int k = 0; k < K; ++k) {
        float wv = WL[k * C + tx];
        acc[0] = fmaf(xb[k], wv, acc[0]);
        acc[1] = fmaf(xb[XS + k], wv, acc[1]);
        acc[2] = fmaf(xb[2 * XS + k], wv, acc[2]);
        acc[3] = fmaf(xb[3 * XS + k], wv, acc[3]);
    }
    #pragma unroll
    for (int i = 0; i < 4; ++i) {
        int row = r0 + ty * 4 + i;
        if (row < N) out[(size_t)row * C + tx] = f2bf(acc[i] * scale[row]);
    }
}

// ---------------- Aggregation ----------------
// out = relu(dinv[i]*(sum_nbr hs[src] + hs[i]) + b) + skips; hs bf16 (dinv[src] folded).
// Lane loads uint2 = 4 bf16; VL=F/4 lanes/row; 8-deep load pipeline, 4 acc chains.
// OBF: write bf16 (packed uint2), else fp32 float4. Skips are bf16.

template <int F, bool OBF>
__global__ __launch_bounds__(256) void agg_kernel(const unsigned short* __restrict__ hs,
        const int* __restrict__ rowptr, const int* __restrict__ col,
        const float* __restrict__ dinv, const float* __restrict__ bias,
        const unsigned short* __restrict__ skipA, const unsigned short* __restrict__ skipB,
        void* __restrict__ outv, int N) {
    constexpr int VL = F / 4;           // lanes per row
    constexpr int NPW = 64 / VL;        // nodes per wave
    int t = threadIdx.x;
    int lane = t & 63, wv = t >> 6;
    int sub = lane / VL, fq = lane % VL;
    int i = (blockIdx.x * 4 + wv) * NPW + sub;
    if (i >= N) return;

    const uint2* hv = (const uint2*)hs;
    float4 a0 = make_float4(0.f, 0.f, 0.f, 0.f);
    float4 a1 = make_float4(0.f, 0.f, 0.f, 0.f);
    float4 a2 = make_float4(0.f, 0.f, 0.f, 0.f);
    float4 a3 = make_float4(0.f, 0.f, 0.f, 0.f);
    bfacc(hv[(size_t)i * VL + fq], a0);   // self-loop term

    int p0 = rowptr[i], p1 = rowptr[i + 1];
    for (int p = p0; p < p1; p += VL) {
        int c = ((p + fq) < p1) ? col[p + fq] : 0;
        int m = min(VL, p1 - p);
        int k = 0;
        for (; k + 8 <= m; k += 8) {
            int s0 = __shfl(c, k + 0, VL), s1 = __shfl(c, k + 1, VL);
            int s2 = __shfl(c, k + 2, VL), s3 = __shfl(c, k + 3, VL);
            int s4 = __shfl(c, k + 4, VL), s5 = __shfl(c, k + 5, VL);
            int s6 = __shfl(c, k + 6, VL), s7 = __shfl(c, k + 7, VL);
            uint2 u0 = hv[(size_t)s0 * VL + fq], u1 = hv[(size_t)s1 * VL + fq];
            uint2 u2 = hv[(size_t)s2 * VL + fq], u3 = hv[(size_t)s3 * VL + fq];
            uint2 u4 = hv[(size_t)s4 * VL + fq], u5 = hv[(size_t)s5 * VL + fq];
            uint2 u6 = hv[(size_t)s6 * VL + fq], u7 = hv[(size_t)s7 * VL + fq];
            bfacc(u0, a0); bfacc(u1, a1); bfacc(u2, a2); bfacc(u3, a3);
            bfacc(u4, a0); bfacc(u5, a1); bfacc(u6, a2); bfacc(u7, a3);
        }
        for (; k + 4 <= m; k += 4) {
            int s0 = __shfl(c, k + 0, VL), s1 = __shfl(c, k + 1, VL);
            int s2 = __shfl(c, k + 2, VL), s3 = __shfl(c, k + 3, VL);
            uint2 u0 = hv[(size_t)s0 * VL + fq], u1 = hv[(size_t)s1 * VL + fq];
            uint2 u2 = hv[(size_t)s2 * VL + fq], u3 = hv[(size_t)s3 * VL + fq];
            bfacc(u0, a0); bfacc(u1, a1); bfacc(u2, a2); bfacc(u3, a3);
        }
        for (; k < m; ++k) {
            int s = __shfl(c, k, VL);
            bfacc(hv[(size_t)s * VL + fq], a1);
        }
    }

    float di = dinv[i];
    float4 b4 = *(const float4*)&bias[fq * 4];
    float4 v;
    v.x = fmaxf(di * ((a0.x + a1.x) + (a2.x + a3.x)) + b4.x, 0.f);
    v.y = fmaxf(di * ((a0.y + a1.y) + (a2.y + a3.y)) + b4.y, 0.f);
    v.z = fmaxf(di * ((a0.z + a1.z) + (a2.z + a3.z)) + b4.z, 0.f);
    v.w = fmaxf(di * ((a0.w + a1.w) + (a2.w + a3.w)) + b4.w, 0.f);
    size_t vo = (size_t)i * VL + fq;
    if (skipA) {
        float4 s4 = bf4(((const uint2*)skipA)[vo]);
        v.x += s4.x; v.y += s4.y; v.z += s4.z; v.w += s4.w;
    }
    if (skipB) {
        float4 s4 = bf4(((const uint2*)skipB)[vo]);
        v.x += s4.x; v.y += s4.y; v.z += s4.z; v.w += s4.w;
    }
    if (OBF) {
        uint2 o;
        o.x = packbf(v.x, v.y);
        o.y = packbf(v.z, v.w);
        ((uint2*)outv)[vo] = o;
    } else {
        ((float4*)outv)[vo] = v;
    }
}

// ---------------- launch ----------------

extern "C" void kernel_launch(void* const* d_in, const int* in_sizes, int n_in,
                              void* d_out, int out_size, void* d_ws, size_t ws_size,
                              hipStream_t stream) {
    const int N = NN;
    const float* x   = (const float*)d_in[0];
    const int*   ei  = (const int*)d_in[1];
    const int    E   = in_sizes[1] / 2;
    const int*   src = ei;
    const int*   dst = ei + E;
    const float* W1 = (const float*)d_in[2],  *b1  = (const float*)d_in[3];
    const float* W2 = (const float*)d_in[4],  *b2  = (const float*)d_in[5];
    const float* W3 = (const float*)d_in[6],  *b3  = (const float*)d_in[7];
    const float* Ws02 = (const float*)d_in[8],  *bs02 = (const float*)d_in[9];
    const float* Ws03 = (const float*)d_in[10], *bs03 = (const float*)d_in[11];
    const float* Ws13 = (const float*)d_in[12], *bs13 = (const float*)d_in[13];

    char* w = (char*)d_ws;
    size_t off = 0;
    auto alloc = [&](size_t bytes) -> void* {
        void* p = w + off;
        off += (bytes + 255) & ~(size_t)255;
        return p;
    };
    int*   bcnt     = (int*)alloc((size_t)NB * 4);
    int*   bstart   = (int*)alloc((size_t)(NB + 1) * 4);
    int*   cursors  = (int*)alloc((size_t)NB * 4);
    int*   rowptr   = (int*)alloc(((size_t)N + 1) * 4);
    float* dinv     = (float*)alloc((size_t)N * 4);
    int*   col      = (int*)alloc((size_t)E * 4);
    unsigned short* hs1 = (unsigned short*)alloc((size_t)N * 64 * 2);   // bf16 [N][64]
    unsigned short* x1  = (unsigned short*)alloc((size_t)N * 64 * 2);   // bf16 [N][64]
    unsigned short* s02 = (unsigned short*)alloc((size_t)N * 32 * 2);   // bf16 [N][32]
    unsigned short* s03 = (unsigned short*)alloc((size_t)N * 16 * 2);   // bf16 [N][16]
    unsigned short* x2  = (unsigned short*)alloc((size_t)N * 32 * 2);   // bf16 [N][32]
    // aliases over dead regions
    unsigned int* packed = (unsigned int*)x1;           // E*4 = 12.8MB == N*64*2; dead before agg1 writes x1
    unsigned short* hs2 = hs1;                          // [N][32] in hs1's first half (hs1 dead after agg1)
    unsigned short* s13 = hs1 + (size_t)N * 32;         // [N][16] in hs1's back half
    unsigned short* hs3 = s02;                          // [N][16] (s02 dead after agg2)

    // ---- CSR build ----
    hipMemsetAsync(bcnt, 0, (size_t)NB * 4, stream);
    bcount_kernel<<<1024, 256, 0, stream>>>(dst, E, bcnt);
    bscan_kernel<<<1, NB, 0, stream>>>(bcnt, bstart, cursors, E);
    multisplit_kernel<<<(E + 4095) / 4096, 256, 0, stream>>>(src, dst, E, cursors, packed);
    bucket_fill_kernel<<<NB, 256, 0, stream>>>(packed, bstart, N, E, rowptr, col, dinv);

    int gb = (N + 63) / 64;
    // layer 1: one x pass -> hs1 (scaled bf16), s02, s03
    gemm3_kernel<<<gb, 256, 0, stream>>>(x, W1, Ws02, bs02, Ws03, bs03, dinv, hs1, s02, s03, N);
    // agg 1 -> x1 (bf16)
    agg_kernel<64, true><<<(N + 15) / 16, 256, 0, stream>>>(hs1, rowptr, col, dinv, b1, nullptr, nullptr, x1, N);
    // layer 2: one x1 pass -> hs2 (scaled bf16), s13 (bf16)
    gemm2b_kernel<64, 32, 16><<<gb, 256, 0, stream>>>(x1, W2, dinv, Ws13, bs13, hs2, s13, N);
    // agg 2 -> x2 (bf16), skip s02
    agg_kernel<32, true><<<(N + 31) / 32, 256, 0, stream>>>(hs2, rowptr, col, dinv, b2, s02, nullptr, x2, N);
    // layer 3
    gemm_l3_kernel<<<gb, 256, 0, stream>>>(x2, W3, dinv, hs3, N);
    // agg 3 -> out (fp32), skips s03 + s13
    agg_kernel<16, false><<<(N + 63) / 64, 256, 0, stream>>>(hs3, rowptr, col, dinv, b3, s03, s13, (float*)d_out, N);
}

// Round 8
// 301.205 us; speedup vs baseline: 1.3732x; 1.1243x over previous
//
#include <hip/hip_runtime.h>

#define NN 100000
#define NB 512            // buckets
#define NPB 196           // nodes per bucket: ceil(100000/512)=196; local dst fits in 8 bits

__device__ inline unsigned short f2bf(float f) {
    unsigned u = __float_as_uint(f);
    return (unsigned short)((u + 0x7FFFu + ((u >> 16) & 1u)) >> 16);
}
__device__ inline unsigned packbf(float a, float b) {
    return (unsigned)f2bf(a) | ((unsigned)f2bf(b) << 16);
}
__device__ inline float bflo(unsigned u) { return __uint_as_float(u << 16); }
__device__ inline float bfhi(unsigned u) { return __uint_as_float(u & 0xFFFF0000u); }

// accumulate 4 bf16 (packed in uint2) into float4
__device__ inline void bfacc(uint2 u, float4& a) {
    a.x += bflo(u.x); a.y += bfhi(u.x); a.z += bflo(u.y); a.w += bfhi(u.y);
}
__device__ inline float4 bf4(uint2 u) {
    return make_float4(bflo(u.x), bfhi(u.x), bflo(u.y), bfhi(u.y));
}

typedef __attribute__((ext_vector_type(8))) short bf16x8;   // 8 bf16 = 4 VGPRs
typedef __attribute__((ext_vector_type(4))) float f32x4;    // MFMA accumulator

// ---------------- CSR build: 2-level bucket multisplit ----------------

__global__ __launch_bounds__(256) void bcount_kernel(const int* __restrict__ dst, int E, int* __restrict__ bcnt) {
    __shared__ int h[NB];
    for (int i = threadIdx.x; i < NB; i += 256) h[i] = 0;
    __syncthreads();
    for (int e = blockIdx.x * 256 + threadIdx.x; e < E; e += gridDim.x * 256)
        atomicAdd(&h[dst[e] / NPB], 1);
    __syncthreads();
    for (int i = threadIdx.x; i < NB; i += 256)
        if (h[i]) atomicAdd(&bcnt[i], h[i]);
}

__global__ __launch_bounds__(512) void bscan_kernel(const int* __restrict__ bcnt, int* __restrict__ bstart,
                                                    int* __restrict__ cursors, int E) {
    __shared__ int sh[NB];
    int t = threadIdx.x;
    int v = bcnt[t];
    sh[t] = v;
    __syncthreads();
    for (int off = 1; off < NB; off <<= 1) {
        int u = (t >= off) ? sh[t - off] : 0;
        __syncthreads();
        sh[t] += u;
        __syncthreads();
    }
    int ex = sh[t] - v;
    bstart[t] = ex;
    cursors[t] = ex;
    if (t == NB - 1) bstart[NB] = E;
}

__global__ __launch_bounds__(256) void multisplit_kernel(const int* __restrict__ src, const int* __restrict__ dst,
                                                         int E, int* __restrict__ cursors,
                                                         unsigned int* __restrict__ packed) {
    __shared__ int cnt[NB];
    __shared__ int base[NB];
    const int CH = 256 * 16;
    int t = threadIdx.x;
    for (long c0 = (long)blockIdx.x * CH; c0 < E; c0 += (long)gridDim.x * CH) {
        for (int i = t; i < NB; i += 256) cnt[i] = 0;
        __syncthreads();
        int s[16], d[16];
        #pragma unroll
        for (int k = 0; k < 16; ++k) {
            long e = c0 + k * 256 + t;
            if (e < E) {
                d[k] = dst[e];
                s[k] = src[e];
                atomicAdd(&cnt[d[k] / NPB], 1);
            } else d[k] = -1;
        }
        __syncthreads();
        for (int i = t; i < NB; i += 256)
            base[i] = cnt[i] ? atomicAdd(&cursors[i], cnt[i]) : 0;
        __syncthreads();
        #pragma unroll
        for (int k = 0; k < 16; ++k) {
            if (d[k] >= 0) {
                int b = d[k] / NPB;
                int ld = d[k] - b * NPB;
                int pos = atomicAdd(&base[b], 1);
                packed[pos] = ((unsigned int)s[k] << 8) | (unsigned int)ld;
            }
        }
        __syncthreads();
    }
}

__global__ __launch_bounds__(256) void bucket_fill_kernel(const unsigned int* __restrict__ packed,
                                                          const int* __restrict__ bstart, int N, int E,
                                                          int* __restrict__ rowptr, int* __restrict__ col,
                                                          float* __restrict__ dinv) {
    int b = blockIdx.x, t = threadIdx.x;
    int e0 = bstart[b], e1 = bstart[b + 1];
    __shared__ int hist[256];
    __shared__ int sh[256];
    __shared__ int cur[256];
    hist[t] = 0;
    __syncthreads();
    for (int e = e0 + t; e < e1; e += 256)
        atomicAdd(&hist[packed[e] & 255u], 1);
    __syncthreads();
    int v = hist[t];
    sh[t] = v;
    __syncthreads();
    for (int off = 1; off < 256; off <<= 1) {
        int u = (t >= off) ? sh[t - off] : 0;
        __syncthreads();
        sh[t] += u;
        __syncthreads();
    }
    int ex = sh[t] - v;
    int node = b * NPB + t;
    if (t < NPB && node < N) {
        rowptr[node] = e0 + ex;
        dinv[node] = rsqrtf(1.0f + (float)v);
    }
    cur[t] = e0 + ex;
    __syncthreads();
    for (int e = e0 + t; e < e1; e += 256) {
        unsigned int p = packed[e];
        int pos = atomicAdd(&cur[p & 255u], 1);
        col[pos] = (int)(p >> 8);
    }
    if (b == 0 && t == 0) rowptr[N] = E;
}

// ---------------- layer-1 weight prepack: Wpk[c][k] = bf16(W^T), c in [0,112) ----------------
// cols 0-63: W1 (K=128,C=64); 64-95: Ws02 (C=32); 96-111: Ws03 (C=16)

__global__ __launch_bounds__(256) void wpack_kernel(const float* __restrict__ W1, const float* __restrict__ Ws02,
                                                    const float* __restrict__ Ws03, unsigned short* __restrict__ Wpk) {
    int i = blockIdx.x * 256 + threadIdx.x;
    if (i >= 112 * 128) return;
    int c = i >> 7, k = i & 127;
    float v;
    if (c < 64)      v = W1[k * 64 + c];
    else if (c < 96) v = Ws02[k * 32 + (c - 64)];
    else             v = Ws03[k * 16 + (c - 96)];
    Wpk[i] = f2bf(v);
}

// ---------------- mfma3: one x pass -> hs1 (64, scaled), s02 (32, bias), s03 (16, bias), all bf16 ----
// 4 waves/block, 16 rows/wave, 7 col-tiles of 16. mfma_f32_16x16x32_bf16:
//   A-frag: lane holds A[row=l&15][k=(l>>4)*8 + e], e=0..7 (contiguous from x row)
//   B-frag: lane holds B[k=(l>>4)*8 + e][col=l&15]  (contiguous from Wpk row = W^T)
//   C/D:    acc[v] = C[row=(l>>4)*4+v][col=l&15]    (m89-verified)
// No LDS, no barriers; Wpk (28.7KB) stays L2-resident.

__global__ __launch_bounds__(256) void mfma3_kernel(const float* __restrict__ X,
        const unsigned short* __restrict__ Wpk, const float* __restrict__ scale,
        const float* __restrict__ bb, const float* __restrict__ bc,
        unsigned short* __restrict__ oa, unsigned short* __restrict__ ob,
        unsigned short* __restrict__ oc, int N) {
    int t = threadIdx.x;
    int wv = t >> 6, l = t & 63;
    int r0 = blockIdx.x * 64 + wv * 16;
    int col = l & 15, g = l >> 4;
    int rowA = r0 + col;                        // A-frag source row (l&15)
    bool okA = rowA < N;
    const float* xrow = X + (size_t)rowA * 128;

    f32x4 acc[7];
    #pragma unroll
    for (int i = 0; i < 7; ++i) acc[i] = (f32x4){0.f, 0.f, 0.f, 0.f};

    #pragma unroll
    for (int s = 0; s < 4; ++s) {
        int k0 = s * 32 + g * 8;
        float4 lo = okA ? *(const float4*)(xrow + k0)     : make_float4(0.f, 0.f, 0.f, 0.f);
        float4 hi = okA ? *(const float4*)(xrow + k0 + 4) : make_float4(0.f, 0.f, 0.f, 0.f);
        union { bf16x8 v; unsigned u[4]; } A;
        A.u[0] = packbf(lo.x, lo.y);
        A.u[1] = packbf(lo.z, lo.w);
        A.u[2] = packbf(hi.x, hi.y);
        A.u[3] = packbf(hi.z, hi.w);
        #pragma unroll
        for (int ct = 0; ct < 7; ++ct) {
            bf16x8 B = *(const bf16x8*)(Wpk + ((size_t)(ct * 16 + col) * 128 + k0));
            acc[ct] = __builtin_amdgcn_mfma_f32_16x16x32_bf16(A.v, B, acc[ct], 0, 0, 0);
        }
    }

    #pragma unroll
    for (int v = 0; v < 4; ++v) {
        int row = r0 + g * 4 + v;
        if (row < N) {
            float sc = scale[row];
            #pragma unroll
            for (int ct = 0; ct < 4; ++ct)
                oa[(size_t)row * 64 + ct * 16 + col] = f2bf(acc[ct][v] * sc);
            #pragma unroll
            for (int ct = 4; ct < 6; ++ct) {
                int c2 = (ct - 4) * 16 + col;
                ob[(size_t)row * 32 + c2] = f2bf(acc[ct][v] + bb[c2]);
            }
            oc[(size_t)row * 16 + col] = f2bf(acc[6][v] + bc[col]);
        }
    }
}

// ---------------- gemm2b: bf16 X input, two bf16 outputs (a: scaled; b: bias) ----------------

template <int K, int C1, int C2>
__global__ __launch_bounds__(256) void gemm2b_kernel(const unsigned short* __restrict__ X,
        const float* __restrict__ Wa, const float* __restrict__ scale,
        const float* __restrict__ Wb, const float* __restrict__ bb,
        unsigned short* __restrict__ oa, unsigned short* __restrict__ ob, int N) {
    constexpr int M1 = C1 / 16, M2 = C2 / 16;
    constexpr int XS = K + 6;
    __shared__ float XL[64 * XS];
    __shared__ float WLa[K * C1];
    __shared__ float WLb[K * C2];
    int t = threadIdx.x;
    int r0 = blockIdx.x * 64;

    for (int i = t; i < K * C1 / 4; i += 256) ((float4*)WLa)[i] = ((const float4*)Wa)[i];
    for (int i = t; i < K * C2 / 4; i += 256) ((float4*)WLb)[i] = ((const float4*)Wb)[i];
    for (int i = t; i < 64 * (K / 4); i += 256) {
        int row = i / (K / 4), g = i % (K / 4);
        uint2 u = make_uint2(0u, 0u);
        if (r0 + row < N) u = ((const uint2*)(X + (size_t)(r0 + row) * K))[g];
        float* p = &XL[row * XS + g * 4];
        *(float2*)p = make_float2(bflo(u.x), bfhi(u.x));
        *(float2*)(p + 2) = make_float2(bflo(u.y), bfhi(u.y));
    }
    __syncthreads();

    int ty = t >> 4, tx = t & 15;
    float acc1[4][M1] = {}, acc2[4][M2] = {};
    const float* xb = &XL[(ty * 4) * XS];
    const float* wba = &WLa[tx * M1];
    const float* wbb = &WLb[tx * M2];
    for (int k = 0; k < K; ++k) {
        float x0 = xb[k], x1 = xb[XS + k], x2 = xb[2 * XS + k], x3 = xb[3 * XS + k];
        float wa[M1], wb2[M2];
        #pragma unroll
        for (int j = 0; j < M1; ++j) wa[j] = wba[k * C1 + j];
        #pragma unroll
        for (int j = 0; j < M2; ++j) wb2[j] = wbb[k * C2 + j];
        #pragma unroll
        for (int j = 0; j < M1; ++j) {
            acc1[0][j] = fmaf(x0, wa[j], acc1[0][j]);
            acc1[1][j] = fmaf(x1, wa[j], acc1[1][j]);
            acc1[2][j] = fmaf(x2, wa[j], acc1[2][j]);
            acc1[3][j] = fmaf(x3, wa[j], acc1[3][j]);
        }
        #pragma unroll
        for (int j = 0; j < M2; ++j) {
            acc2[0][j] = fmaf(x0, wb2[j], acc2[0][j]);
            acc2[1][j] = fmaf(x1, wb2[j], acc2[1][j]);
            acc2[2][j] = fmaf(x2, wb2[j], acc2[2][j]);
            acc2[3][j] = fmaf(x3, wb2[j], acc2[3][j]);
        }
    }

    #pragma unroll
    for (int i = 0; i < 4; ++i) {
        int row = r0 + ty * 4 + i;
        if (row < N) {
            float sc = scale[row];
            ((unsigned*)(oa + (size_t)row * C1))[tx] = packbf(acc1[i][0] * sc, acc1[i][1] * sc);
            ob[(size_t)row * C2 + tx] = f2bf(acc2[i][0] + bb[tx]);
        }
    }
}

// ---------------- gemm_l3: bf16 X [N][32] -> hs3 [N][16] bf16, scaled ----------------

__global__ __launch_bounds__(256) void gemm_l3_kernel(const unsigned short* __restrict__ X,
        const float* __restrict__ W, const float* __restrict__ scale,
        unsigned short* __restrict__ out, int N) {
    constexpr int K = 32, C = 16, XS = K + 6;
    __shared__ float XL[64 * XS];
    __shared__ float WL[K * C];
    int t = threadIdx.x;
    int r0 = blockIdx.x * 64;

    for (int i = t; i < K * C / 4; i += 256) ((float4*)WL)[i] = ((const float4*)W)[i];
    for (int i = t; i < 64 * (K / 4); i += 256) {
        int row = i / (K / 4), g = i % (K / 4);
        uint2 u = make_uint2(0u, 0u);
        if (r0 + row < N) u = ((const uint2*)(X + (size_t)(r0 + row) * K))[g];
        float* p = &XL[row * XS + g * 4];
        *(float2*)p = make_float2(bflo(u.x), bfhi(u.x));
        *(float2*)(p + 2) = make_float2(bflo(u.y), bfhi(u.y));
    }
    __syncthreads();

    int ty = t >> 4, tx = t & 15;
    float acc[4] = {0.f, 0.f, 0.f, 0.f};
    const float* xb = &XL[(ty * 4) * XS];
    for (int k = 0; k < K; ++k) {
        float wv = WL[k * C + tx];
        acc[0] = fmaf(xb[k], wv, acc[0]);
        acc[1] = fmaf(xb[XS + k], wv, acc[1]);
        acc[2] = fmaf(xb[2 * XS + k], wv, acc[2]);
        acc[3] = fmaf(xb[3 * XS + k], wv, acc[3]);
    }
    #pragma unroll
    for (int i = 0; i < 4; ++i) {
        int row = r0 + ty * 4 + i;
        if (row < N) out[(size_t)row * C + tx] = f2bf(acc[i] * scale[row]);
    }
}

// ---------------- Aggregation ----------------
// out = relu(dinv[i]*(sum_nbr hs[src] + hs[i]) + b) + skips; hs bf16 (dinv[src] folded).
// Lane loads uint2 = 4 bf16; VL=F/4 lanes/row; 8-deep load pipeline, 4 acc chains.
// OBF: write bf16 (packed uint2), else fp32 float4. Skips are bf16.

template <int F, bool OBF>
__global__ __launch_bounds__(256) void agg_kernel(const unsigned short* __restrict__ hs,
        const int* __restrict__ rowptr, const int* __restrict__ col,
        const float* __restrict__ dinv, const float* __restrict__ bias,
        const unsigned short* __restrict__ skipA, const unsigned short* __restrict__ skipB,
        void* __restrict__ outv, int N) {
    constexpr int VL = F / 4;           // lanes per row
    constexpr int NPW = 64 / VL;        // nodes per wave
    int t = threadIdx.x;
    int lane = t & 63, wv = t >> 6;
    int sub = lane / VL, fq = lane % VL;
    int i = (blockIdx.x * 4 + wv) * NPW + sub;
    if (i >= N) return;

    const uint2* hv = (const uint2*)hs;
    float4 a0 = make_float4(0.f, 0.f, 0.f, 0.f);
    float4 a1 = make_float4(0.f, 0.f, 0.f, 0.f);
    float4 a2 = make_float4(0.f, 0.f, 0.f, 0.f);
    float4 a3 = make_float4(0.f, 0.f, 0.f, 0.f);
    bfacc(hv[(size_t)i * VL + fq], a0);   // self-loop term

    int p0 = rowptr[i], p1 = rowptr[i + 1];
    for (int p = p0; p < p1; p += VL) {
        int c = ((p + fq) < p1) ? col[p + fq] : 0;
        int m = min(VL, p1 - p);
        int k = 0;
        for (; k + 8 <= m; k += 8) {
            int s0 = __shfl(c, k + 0, VL), s1 = __shfl(c, k + 1, VL);
            int s2 = __shfl(c, k + 2, VL), s3 = __shfl(c, k + 3, VL);
            int s4 = __shfl(c, k + 4, VL), s5 = __shfl(c, k + 5, VL);
            int s6 = __shfl(c, k + 6, VL), s7 = __shfl(c, k + 7, VL);
            uint2 u0 = hv[(size_t)s0 * VL + fq], u1 = hv[(size_t)s1 * VL + fq];
            uint2 u2 = hv[(size_t)s2 * VL + fq], u3 = hv[(size_t)s3 * VL + fq];
            uint2 u4 = hv[(size_t)s4 * VL + fq], u5 = hv[(size_t)s5 * VL + fq];
            uint2 u6 = hv[(size_t)s6 * VL + fq], u7 = hv[(size_t)s7 * VL + fq];
            bfacc(u0, a0); bfacc(u1, a1); bfacc(u2, a2); bfacc(u3, a3);
            bfacc(u4, a0); bfacc(u5, a1); bfacc(u6, a2); bfacc(u7, a3);
        }
        for (; k + 4 <= m; k += 4) {
            int s0 = __shfl(c, k + 0, VL), s1 = __shfl(c, k + 1, VL);
            int s2 = __shfl(c, k + 2, VL), s3 = __shfl(c, k + 3, VL);
            uint2 u0 = hv[(size_t)s0 * VL + fq], u1 = hv[(size_t)s1 * VL + fq];
            uint2 u2 = hv[(size_t)s2 * VL + fq], u3 = hv[(size_t)s3 * VL + fq];
            bfacc(u0, a0); bfacc(u1, a1); bfacc(u2, a2); bfacc(u3, a3);
        }
        for (; k < m; ++k) {
            int s = __shfl(c, k, VL);
            bfacc(hv[(size_t)s * VL + fq], a1);
        }
    }

    float di = dinv[i];
    float4 b4 = *(const float4*)&bias[fq * 4];
    float4 v;
    v.x = fmaxf(di * ((a0.x + a1.x) + (a2.x + a3.x)) + b4.x, 0.f);
    v.y = fmaxf(di * ((a0.y + a1.y) + (a2.y + a3.y)) + b4.y, 0.f);
    v.z = fmaxf(di * ((a0.z + a1.z) + (a2.z + a3.z)) + b4.z, 0.f);
    v.w = fmaxf(di * ((a0.w + a1.w) + (a2.w + a3.w)) + b4.w, 0.f);
    size_t vo = (size_t)i * VL + fq;
    if (skipA) {
        float4 s4 = bf4(((const uint2*)skipA)[vo]);
        v.x += s4.x; v.y += s4.y; v.z += s4.z; v.w += s4.w;
    }
    if (skipB) {
        float4 s4 = bf4(((const uint2*)skipB)[vo]);
        v.x += s4.x; v.y += s4.y; v.z += s4.z; v.w += s4.w;
    }
    if (OBF) {
        uint2 o;
        o.x = packbf(v.x, v.y);
        o.y = packbf(v.z, v.w);
        ((uint2*)outv)[vo] = o;
    } else {
        ((float4*)outv)[vo] = v;
    }
}

// ---------------- launch ----------------

extern "C" void kernel_launch(void* const* d_in, const int* in_sizes, int n_in,
                              void* d_out, int out_size, void* d_ws, size_t ws_size,
                              hipStream_t stream) {
    const int N = NN;
    const float* x   = (const float*)d_in[0];
    const int*   ei  = (const int*)d_in[1];
    const int    E   = in_sizes[1] / 2;
    const int*   src = ei;
    const int*   dst = ei + E;
    const float* W1 = (const float*)d_in[2],  *b1  = (const float*)d_in[3];
    const float* W2 = (const float*)d_in[4],  *b2  = (const float*)d_in[5];
    const float* W3 = (const float*)d_in[6],  *b3  = (const float*)d_in[7];
    const float* Ws02 = (const float*)d_in[8],  *bs02 = (const float*)d_in[9];
    const float* Ws03 = (const float*)d_in[10], *bs03 = (const float*)d_in[11];
    const float* Ws13 = (const float*)d_in[12], *bs13 = (const float*)d_in[13];

    char* w = (char*)d_ws;
    size_t off = 0;
    auto alloc = [&](size_t bytes) -> void* {
        void* p = w + off;
        off += (bytes + 255) & ~(size_t)255;
        return p;
    };
    int*   bcnt     = (int*)alloc((size_t)NB * 4);
    int*   bstart   = (int*)alloc((size_t)(NB + 1) * 4);
    int*   cursors  = (int*)alloc((size_t)NB * 4);
    int*   rowptr   = (int*)alloc(((size_t)N + 1) * 4);
    float* dinv     = (float*)alloc((size_t)N * 4);
    int*   col      = (int*)alloc((size_t)E * 4);
    unsigned short* Wpk = (unsigned short*)alloc((size_t)112 * 128 * 2);
    unsigned short* hs1 = (unsigned short*)alloc((size_t)N * 64 * 2);   // bf16 [N][64]
    unsigned short* x1  = (unsigned short*)alloc((size_t)N * 64 * 2);   // bf16 [N][64]
    unsigned short* s02 = (unsigned short*)alloc((size_t)N * 32 * 2);   // bf16 [N][32]
    unsigned short* s03 = (unsigned short*)alloc((size_t)N * 16 * 2);   // bf16 [N][16]
    unsigned short* x2  = (unsigned short*)alloc((size_t)N * 32 * 2);   // bf16 [N][32]
    // aliases over dead regions
    unsigned int* packed = (unsigned int*)x1;           // E*4 = 12.8MB == N*64*2; dead before agg1 writes x1
    unsigned short* hs2 = hs1;                          // [N][32] in hs1's first half (hs1 dead after agg1)
    unsigned short* s13 = hs1 + (size_t)N * 32;         // [N][16] in hs1's back half
    unsigned short* hs3 = s02;                          // [N][16] (s02 dead after agg2)

    // ---- weight prepack (L2-warm before mfma3) ----
    wpack_kernel<<<(112 * 128 + 255) / 256, 256, 0, stream>>>(W1, Ws02, Ws03, Wpk);

    // ---- CSR build ----
    hipMemsetAsync(bcnt, 0, (size_t)NB * 4, stream);
    bcount_kernel<<<1024, 256, 0, stream>>>(dst, E, bcnt);
    bscan_kernel<<<1, NB, 0, stream>>>(bcnt, bstart, cursors, E);
    multisplit_kernel<<<(E + 4095) / 4096, 256, 0, stream>>>(src, dst, E, cursors, packed);
    bucket_fill_kernel<<<NB, 256, 0, stream>>>(packed, bstart, N, E, rowptr, col, dinv);

    int gb = (N + 63) / 64;
    // layer 1: one x pass via MFMA -> hs1 (scaled bf16), s02, s03
    mfma3_kernel<<<gb, 256, 0, stream>>>(x, Wpk, dinv, bs02, bs03, hs1, s02, s03, N);
    // agg 1 -> x1 (bf16)
    agg_kernel<64, true><<<(N + 15) / 16, 256, 0, stream>>>(hs1, rowptr, col, dinv, b1, nullptr, nullptr, x1, N);
    // layer 2: one x1 pass -> hs2 (scaled bf16), s13 (bf16)
    gemm2b_kernel<64, 32, 16><<<gb, 256, 0, stream>>>(x1, W2, dinv, Ws13, bs13, hs2, s13, N);
    // agg 2 -> x2 (bf16), skip s02
    agg_kernel<32, true><<<(N + 31) / 32, 256, 0, stream>>>(hs2, rowptr, col, dinv, b2, s02, nullptr, x2, N);
    // layer 3
    gemm_l3_kernel<<<gb, 256, 0, stream>>>(x2, W3, dinv, hs3, N);
    // agg 3 -> out (fp32), skips s03 + s13
    agg_kernel<16, false><<<(N + 63) / 64, 256, 0, stream>>>(hs3, rowptr, col, dinv, b3, s03, s13, (float*)d_out, N);
}

// Round 9
// 258.816 us; speedup vs baseline: 1.5981x; 1.1638x over previous
//
#include <hip/hip_runtime.h>

#define NN 100000
#define NB 512            // buckets
#define NPB 196           // nodes per bucket: ceil(100000/512)=196; local dst fits in 8 bits

__device__ inline unsigned short f2bf(float f) {
    unsigned u = __float_as_uint(f);
    return (unsigned short)((u + 0x7FFFu + ((u >> 16) & 1u)) >> 16);
}
__device__ inline unsigned packbf(float a, float b) {
    return (unsigned)f2bf(a) | ((unsigned)f2bf(b) << 16);
}
__device__ inline float bflo(unsigned u) { return __uint_as_float(u << 16); }
__device__ inline float bfhi(unsigned u) { return __uint_as_float(u & 0xFFFF0000u); }
__device__ inline float4 bf4(uint2 u) {
    return make_float4(bflo(u.x), bfhi(u.x), bflo(u.y), bfhi(u.y));
}

// ---- fp8 e4m3 (hardware cvt; encode+decode use same HW format -> consistent) ----
__device__ inline void fp8acc(unsigned u, float4& a) {
    auto lo = __builtin_amdgcn_cvt_pk_f32_fp8((int)u, false);   // bytes 0,1
    auto hi = __builtin_amdgcn_cvt_pk_f32_fp8((int)u, true);    // bytes 2,3
    a.x += lo[0]; a.y += lo[1]; a.z += hi[0]; a.w += hi[1];
}
__device__ inline unsigned char f2fp8(float v) {
    return (unsigned char)(__builtin_amdgcn_cvt_pk_fp8_f32(v, 0.f, 0, false) & 0xFF);
}
__device__ inline unsigned short f2fp8x2(float a, float b) {
    return (unsigned short)(__builtin_amdgcn_cvt_pk_fp8_f32(a, b, 0, false) & 0xFFFF);
}

typedef __attribute__((ext_vector_type(8))) short bf16x8;   // 8 bf16 = 4 VGPRs
typedef __attribute__((ext_vector_type(4))) float f32x4;    // MFMA accumulator

// ---------------- CSR build: 2-level bucket multisplit ----------------

__global__ __launch_bounds__(256) void bcount_kernel(const int* __restrict__ dst, int E, int* __restrict__ bcnt) {
    __shared__ int h[NB];
    for (int i = threadIdx.x; i < NB; i += 256) h[i] = 0;
    __syncthreads();
    for (int e = blockIdx.x * 256 + threadIdx.x; e < E; e += gridDim.x * 256)
        atomicAdd(&h[dst[e] / NPB], 1);
    __syncthreads();
    for (int i = threadIdx.x; i < NB; i += 256)
        if (h[i]) atomicAdd(&bcnt[i], h[i]);
}

__global__ __launch_bounds__(512) void bscan_kernel(const int* __restrict__ bcnt, int* __restrict__ bstart,
                                                    int* __restrict__ cursors, int E) {
    __shared__ int sh[NB];
    int t = threadIdx.x;
    int v = bcnt[t];
    sh[t] = v;
    __syncthreads();
    for (int off = 1; off < NB; off <<= 1) {
        int u = (t >= off) ? sh[t - off] : 0;
        __syncthreads();
        sh[t] += u;
        __syncthreads();
    }
    int ex = sh[t] - v;
    bstart[t] = ex;
    cursors[t] = ex;
    if (t == NB - 1) bstart[NB] = E;
}

__global__ __launch_bounds__(256) void multisplit_kernel(const int* __restrict__ src, const int* __restrict__ dst,
                                                         int E, int* __restrict__ cursors,
                                                         unsigned int* __restrict__ packed) {
    __shared__ int cnt[NB];
    __shared__ int base[NB];
    const int CH = 256 * 16;
    int t = threadIdx.x;
    for (long c0 = (long)blockIdx.x * CH; c0 < E; c0 += (long)gridDim.x * CH) {
        for (int i = t; i < NB; i += 256) cnt[i] = 0;
        __syncthreads();
        int s[16], d[16];
        #pragma unroll
        for (int k = 0; k < 16; ++k) {
            long e = c0 + k * 256 + t;
            if (e < E) {
                d[k] = dst[e];
                s[k] = src[e];
                atomicAdd(&cnt[d[k] / NPB], 1);
            } else d[k] = -1;
        }
        __syncthreads();
        for (int i = t; i < NB; i += 256)
            base[i] = cnt[i] ? atomicAdd(&cursors[i], cnt[i]) : 0;
        __syncthreads();
        #pragma unroll
        for (int k = 0; k < 16; ++k) {
            if (d[k] >= 0) {
                int b = d[k] / NPB;
                int ld = d[k] - b * NPB;
                int pos = atomicAdd(&base[b], 1);
                packed[pos] = ((unsigned int)s[k] << 8) | (unsigned int)ld;
            }
        }
        __syncthreads();
    }
}

__global__ __launch_bounds__(256) void bucket_fill_kernel(const unsigned int* __restrict__ packed,
                                                          const int* __restrict__ bstart, int N, int E,
                                                          int* __restrict__ rowptr, int* __restrict__ col,
                                                          float* __restrict__ dinv) {
    int b = blockIdx.x, t = threadIdx.x;
    int e0 = bstart[b], e1 = bstart[b + 1];
    __shared__ int hist[256];
    __shared__ int sh[256];
    __shared__ int cur[256];
    hist[t] = 0;
    __syncthreads();
    for (int e = e0 + t; e < e1; e += 256)
        atomicAdd(&hist[packed[e] & 255u], 1);
    __syncthreads();
    int v = hist[t];
    sh[t] = v;
    __syncthreads();
    for (int off = 1; off < 256; off <<= 1) {
        int u = (t >= off) ? sh[t - off] : 0;
        __syncthreads();
        sh[t] += u;
        __syncthreads();
    }
    int ex = sh[t] - v;
    int node = b * NPB + t;
    if (t < NPB && node < N) {
        rowptr[node] = e0 + ex;
        dinv[node] = rsqrtf(1.0f + (float)v);
    }
    cur[t] = e0 + ex;
    __syncthreads();
    for (int e = e0 + t; e < e1; e += 256) {
        unsigned int p = packed[e];
        int pos = atomicAdd(&cur[p & 255u], 1);
        col[pos] = (int)(p >> 8);
    }
    if (b == 0 && t == 0) rowptr[N] = E;
}

// ---------------- layer-1 weight prepack: Wpk[c][k] = bf16(W^T), c in [0,112); also zeros bcnt ----

__global__ __launch_bounds__(256) void wpack_kernel(const float* __restrict__ W1, const float* __restrict__ Ws02,
                                                    const float* __restrict__ Ws03, unsigned short* __restrict__ Wpk,
                                                    int* __restrict__ bcnt) {
    if (blockIdx.x < 2) bcnt[blockIdx.x * 256 + threadIdx.x] = 0;
    int i = blockIdx.x * 256 + threadIdx.x;
    if (i >= 112 * 128) return;
    int c = i >> 7, k = i & 127;
    float v;
    if (c < 64)      v = W1[k * 64 + c];
    else if (c < 96) v = Ws02[k * 32 + (c - 64)];
    else             v = Ws03[k * 16 + (c - 96)];
    Wpk[i] = f2bf(v);
}

// ---------------- mfma3: one x pass -> hs1 (64, scaled, fp8), s02 (32, bias, bf16), s03 (16, bias, bf16) ----

__global__ __launch_bounds__(256) void mfma3_kernel(const float* __restrict__ X,
        const unsigned short* __restrict__ Wpk, const float* __restrict__ scale,
        const float* __restrict__ bb, const float* __restrict__ bc,
        unsigned char* __restrict__ oa, unsigned short* __restrict__ ob,
        unsigned short* __restrict__ oc, int N) {
    int t = threadIdx.x;
    int wv = t >> 6, l = t & 63;
    int r0 = blockIdx.x * 64 + wv * 16;
    int col = l & 15, g = l >> 4;
    int rowA = r0 + col;
    bool okA = rowA < N;
    const float* xrow = X + (size_t)rowA * 128;

    f32x4 acc[7];
    #pragma unroll
    for (int i = 0; i < 7; ++i) acc[i] = (f32x4){0.f, 0.f, 0.f, 0.f};

    #pragma unroll
    for (int s = 0; s < 4; ++s) {
        int k0 = s * 32 + g * 8;
        float4 lo = okA ? *(const float4*)(xrow + k0)     : make_float4(0.f, 0.f, 0.f, 0.f);
        float4 hi = okA ? *(const float4*)(xrow + k0 + 4) : make_float4(0.f, 0.f, 0.f, 0.f);
        union { bf16x8 v; unsigned u[4]; } A;
        A.u[0] = packbf(lo.x, lo.y);
        A.u[1] = packbf(lo.z, lo.w);
        A.u[2] = packbf(hi.x, hi.y);
        A.u[3] = packbf(hi.z, hi.w);
        #pragma unroll
        for (int ct = 0; ct < 7; ++ct) {
            bf16x8 B = *(const bf16x8*)(Wpk + ((size_t)(ct * 16 + col) * 128 + k0));
            acc[ct] = __builtin_amdgcn_mfma_f32_16x16x32_bf16(A.v, B, acc[ct], 0, 0, 0);
        }
    }

    #pragma unroll
    for (int v = 0; v < 4; ++v) {
        int row = r0 + g * 4 + v;
        if (row < N) {
            float sc = scale[row];
            #pragma unroll
            for (int ct = 0; ct < 4; ++ct)
                oa[(size_t)row * 64 + ct * 16 + col] = f2fp8(acc[ct][v] * sc);
            #pragma unroll
            for (int ct = 4; ct < 6; ++ct) {
                int c2 = (ct - 4) * 16 + col;
                ob[(size_t)row * 32 + c2] = f2bf(acc[ct][v] + bb[c2]);
            }
            oc[(size_t)row * 16 + col] = f2bf(acc[6][v] + bc[col]);
        }
    }
}

// ---------------- gemm2b: bf16 X input -> hs2 (fp8, scaled), s13 (bf16, bias) ----------------

template <int K, int C1, int C2>
__global__ __launch_bounds__(256) void gemm2b_kernel(const unsigned short* __restrict__ X,
        const float* __restrict__ Wa, const float* __restrict__ scale,
        const float* __restrict__ Wb, const float* __restrict__ bb,
        unsigned char* __restrict__ oa, unsigned short* __restrict__ ob, int N) {
    constexpr int M1 = C1 / 16, M2 = C2 / 16;
    constexpr int XS = K + 6;
    __shared__ float XL[64 * XS];
    __shared__ float WLa[K * C1];
    __shared__ float WLb[K * C2];
    int t = threadIdx.x;
    int r0 = blockIdx.x * 64;

    for (int i = t; i < K * C1 / 4; i += 256) ((float4*)WLa)[i] = ((const float4*)Wa)[i];
    for (int i = t; i < K * C2 / 4; i += 256) ((float4*)WLb)[i] = ((const float4*)Wb)[i];
    for (int i = t; i < 64 * (K / 4); i += 256) {
        int row = i / (K / 4), g = i % (K / 4);
        uint2 u = make_uint2(0u, 0u);
        if (r0 + row < N) u = ((const uint2*)(X + (size_t)(r0 + row) * K))[g];
        float* p = &XL[row * XS + g * 4];
        *(float2*)p = make_float2(bflo(u.x), bfhi(u.x));
        *(float2*)(p + 2) = make_float2(bflo(u.y), bfhi(u.y));
    }
    __syncthreads();

    int ty = t >> 4, tx = t & 15;
    float acc1[4][M1] = {}, acc2[4][M2] = {};
    const float* xb = &XL[(ty * 4) * XS];
    const float* wba = &WLa[tx * M1];
    const float* wbb = &WLb[tx * M2];
    for (int k = 0; k < K; ++k) {
        float x0 = xb[k], x1 = xb[XS + k], x2 = xb[2 * XS + k], x3 = xb[3 * XS + k];
        float wa[M1], wb2[M2];
        #pragma unroll
        for (int j = 0; j < M1; ++j) wa[j] = wba[k * C1 + j];
        #pragma unroll
        for (int j = 0; j < M2; ++j) wb2[j] = wbb[k * C2 + j];
        #pragma unroll
        for (int j = 0; j < M1; ++j) {
            acc1[0][j] = fmaf(x0, wa[j], acc1[0][j]);
            acc1[1][j] = fmaf(x1, wa[j], acc1[1][j]);
            acc1[2][j] = fmaf(x2, wa[j], acc1[2][j]);
            acc1[3][j] = fmaf(x3, wa[j], acc1[3][j]);
        }
        #pragma unroll
        for (int j = 0; j < M2; ++j) {
            acc2[0][j] = fmaf(x0, wb2[j], acc2[0][j]);
            acc2[1][j] = fmaf(x1, wb2[j], acc2[1][j]);
            acc2[2][j] = fmaf(x2, wb2[j], acc2[2][j]);
            acc2[3][j] = fmaf(x3, wb2[j], acc2[3][j]);
        }
    }

    #pragma unroll
    for (int i = 0; i < 4; ++i) {
        int row = r0 + ty * 4 + i;
        if (row < N) {
            float sc = scale[row];
            *(unsigned short*)(oa + (size_t)row * C1 + tx * 2) = f2fp8x2(acc1[i][0] * sc, acc1[i][1] * sc);
            ob[(size_t)row * C2 + tx] = f2bf(acc2[i][0] + bb[tx]);
        }
    }
}

// ---------------- gemm_l3: bf16 X [N][32] -> hs3 [N][16] fp8, scaled ----------------

__global__ __launch_bounds__(256) void gemm_l3_kernel(const unsigned short* __restrict__ X,
        const float* __restrict__ W, const float* __restrict__ scale,
        unsigned char* __restrict__ out, int N) {
    constexpr int K = 32, C = 16, XS = K + 6;
    __shared__ float XL[64 * XS];
    __shared__ float WL[K * C];
    int t = threadIdx.x;
    int r0 = blockIdx.x * 64;

    for (int i = t; i < K * C / 4; i += 256) ((float4*)WL)[i] = ((const float4*)W)[i];
    for (int i = t; i < 64 * (K / 4); i += 256) {
        int row = i / (K / 4), g = i % (K / 4);
        uint2 u = make_uint2(0u, 0u);
        if (r0 + row < N) u = ((const uint2*)(X + (size_t)(r0 + row) * K))[g];
        float* p = &XL[row * XS + g * 4];
        *(float2*)p = make_float2(bflo(u.x), bfhi(u.x));
        *(float2*)(p + 2) = make_float2(bflo(u.y), bfhi(u.y));
    }
    __syncthreads();

    int ty = t >> 4, tx = t & 15;
    float acc[4] = {0.f, 0.f, 0.f, 0.f};
    const float* xb = &XL[(ty * 4) * XS];
    for (int k = 0; k < K; ++k) {
        float wv = WL[k * C + tx];
        acc[0] = fmaf(xb[k], wv, acc[0]);
        acc[1] = fmaf(xb[XS + k], wv, acc[1]);
        acc[2] = fmaf(xb[2 * XS + k], wv, acc[2]);
        acc[3] = fmaf(xb[3 * XS + k], wv, acc[3]);
    }
    #pragma unroll
    for (int i = 0; i < 4; ++i) {
        int row = r0 + ty * 4 + i;
        if (row < N) out[(size_t)row * C + tx] = f2fp8(acc[i] * scale[row]);
    }
}

// ---------------- Aggregation (fp8 hs gather) ----------------
// out = relu(dinv[i]*(sum_nbr hs[src] + hs[i]) + b) + skips.
// hs fp8 e4m3 (dinv[src] folded). FPL = fp8 features per lane (8 -> uint2, 4 -> uint).
// Window of W=8 edges with CR=W/VL col regs keeps 8 gathers in flight for any VL.
// OBF: write bf16, else fp32. Skips are bf16.

template <int F, int FPL, bool OBF>
__global__ __launch_bounds__(256) void agg_kernel(const unsigned char* __restrict__ hs,
        const int* __restrict__ rowptr, const int* __restrict__ col,
        const float* __restrict__ dinv, const float* __restrict__ bias,
        const unsigned short* __restrict__ skipA, const unsigned short* __restrict__ skipB,
        void* __restrict__ outv, int N) {
    constexpr int VL = F / FPL;         // lanes per row
    constexpr int NPW = 64 / VL;        // nodes per wave
    constexpr int W = 8;                // edge window
    constexpr int CR = W / VL;          // col regs per lane
    int t = threadIdx.x;
    int lane = t & 63, wv = t >> 6;
    int sub = lane / VL, fq = lane % VL;
    int i = (blockIdx.x * 4 + wv) * NPW + sub;
    if (i >= N) return;

    float4 aA0 = make_float4(0.f, 0.f, 0.f, 0.f);
    float4 aA1 = make_float4(0.f, 0.f, 0.f, 0.f);
    float4 aB0 = make_float4(0.f, 0.f, 0.f, 0.f);
    float4 aB1 = make_float4(0.f, 0.f, 0.f, 0.f);

    {   // self-loop term
        const unsigned char* hrow = hs + (size_t)i * F + fq * FPL;
        if constexpr (FPL == 8) {
            uint2 u = *(const uint2*)hrow;
            fp8acc(u.x, aA0); fp8acc(u.y, aB0);
        } else {
            fp8acc(*(const unsigned*)hrow, aA0);
        }
    }

    int p0 = rowptr[i], p1 = rowptr[i + 1];
    int p = p0;
    for (; p + W <= p1; p += W) {
        int cw[CR];
        #pragma unroll
        for (int j = 0; j < CR; ++j) cw[j] = col[p + fq + j * VL];
        #pragma unroll
        for (int k = 0; k < W; ++k) {
            int s = __shfl(cw[k / VL], k % VL, VL);
            const unsigned char* sp = hs + (size_t)s * F + fq * FPL;
            if constexpr (FPL == 8) {
                uint2 u = *(const uint2*)sp;
                if (k & 1) { fp8acc(u.x, aA1); fp8acc(u.y, aB1); }
                else       { fp8acc(u.x, aA0); fp8acc(u.y, aB0); }
            } else {
                if (k & 1) fp8acc(*(const unsigned*)sp, aA1);
                else       fp8acc(*(const unsigned*)sp, aA0);
            }
        }
    }
    for (; p < p1; p += VL) {
        int c = (p + fq < p1) ? col[p + fq] : 0;
        int m = min(VL, p1 - p);
        for (int k = 0; k < m; ++k) {
            int s = __shfl(c, k, VL);
            const unsigned char* sp = hs + (size_t)s * F + fq * FPL;
            if constexpr (FPL == 8) {
                uint2 u = *(const uint2*)sp;
                fp8acc(u.x, aA1); fp8acc(u.y, aB1);
            } else {
                fp8acc(*(const unsigned*)sp, aA1);
            }
        }
    }

    float di = dinv[i];
    int fb = fq * FPL;
    float o[FPL];
    o[0] = fmaxf(di * (aA0.x + aA1.x) + bias[fb + 0], 0.f);
    o[1] = fmaxf(di * (aA0.y + aA1.y) + bias[fb + 1], 0.f);
    o[2] = fmaxf(di * (aA0.z + aA1.z) + bias[fb + 2], 0.f);
    o[3] = fmaxf(di * (aA0.w + aA1.w) + bias[fb + 3], 0.f);
    if constexpr (FPL == 8) {
        o[4] = fmaxf(di * (aB0.x + aB1.x) + bias[fb + 4], 0.f);
        o[5] = fmaxf(di * (aB0.y + aB1.y) + bias[fb + 5], 0.f);
        o[6] = fmaxf(di * (aB0.z + aB1.z) + bias[fb + 6], 0.f);
        o[7] = fmaxf(di * (aB0.w + aB1.w) + bias[fb + 7], 0.f);
    }
    if (skipA) {
        const unsigned short* sp = skipA + (size_t)i * F + fb;
        if constexpr (FPL == 8) {
            uint4 sa = *(const uint4*)sp;
            float4 s0 = bf4(make_uint2(sa.x, sa.y)), s1 = bf4(make_uint2(sa.z, sa.w));
            o[0] += s0.x; o[1] += s0.y; o[2] += s0.z; o[3] += s0.w;
            o[4] += s1.x; o[5] += s1.y; o[6] += s1.z; o[7] += s1.w;
        } else {
            float4 s0 = bf4(*(const uint2*)sp);
            o[0] += s0.x; o[1] += s0.y; o[2] += s0.z; o[3] += s0.w;
        }
    }
    if (skipB) {
        const unsigned short* sp = skipB + (size_t)i * F + fb;
        if constexpr (FPL == 8) {
            uint4 sa = *(const uint4*)sp;
            float4 s0 = bf4(make_uint2(sa.x, sa.y)), s1 = bf4(make_uint2(sa.z, sa.w));
            o[0] += s0.x; o[1] += s0.y; o[2] += s0.z; o[3] += s0.w;
            o[4] += s1.x; o[5] += s1.y; o[6] += s1.z; o[7] += s1.w;
        } else {
            float4 s0 = bf4(*(const uint2*)sp);
            o[0] += s0.x; o[1] += s0.y; o[2] += s0.z; o[3] += s0.w;
        }
    }

    if constexpr (OBF) {
        unsigned short* op = (unsigned short*)outv + (size_t)i * F + fb;
        if constexpr (FPL == 8) {
            uint4 w4;
            w4.x = packbf(o[0], o[1]); w4.y = packbf(o[2], o[3]);
            w4.z = packbf(o[4], o[5]); w4.w = packbf(o[6], o[7]);
            *(uint4*)op = w4;
        } else {
            uint2 w2;
            w2.x = packbf(o[0], o[1]); w2.y = packbf(o[2], o[3]);
            *(uint2*)op = w2;
        }
    } else {
        *(float4*)((float*)outv + (size_t)i * F + fb) = make_float4(o[0], o[1], o[2], o[3]);
    }
}

// ---------------- launch ----------------

extern "C" void kernel_launch(void* const* d_in, const int* in_sizes, int n_in,
                              void* d_out, int out_size, void* d_ws, size_t ws_size,
                              hipStream_t stream) {
    const int N = NN;
    const float* x   = (const float*)d_in[0];
    const int*   ei  = (const int*)d_in[1];
    const int    E   = in_sizes[1] / 2;
    const int*   src = ei;
    const int*   dst = ei + E;
    const float* W1 = (const float*)d_in[2],  *b1  = (const float*)d_in[3];
    const float* W2 = (const float*)d_in[4],  *b2  = (const float*)d_in[5];
    const float* W3 = (const float*)d_in[6],  *b3  = (const float*)d_in[7];
    const float* Ws02 = (const float*)d_in[8],  *bs02 = (const float*)d_in[9];
    const float* Ws03 = (const float*)d_in[10], *bs03 = (const float*)d_in[11];
    const float* Ws13 = (const float*)d_in[12], *bs13 = (const float*)d_in[13];

    char* w = (char*)d_ws;
    size_t off = 0;
    auto alloc = [&](size_t bytes) -> void* {
        void* p = w + off;
        off += (bytes + 255) & ~(size_t)255;
        return p;
    };
    int*   bcnt     = (int*)alloc((size_t)NB * 4);
    int*   bstart   = (int*)alloc((size_t)(NB + 1) * 4);
    int*   cursors  = (int*)alloc((size_t)NB * 4);
    int*   rowptr   = (int*)alloc(((size_t)N + 1) * 4);
    float* dinv     = (float*)alloc((size_t)N * 4);
    int*   col      = (int*)alloc((size_t)E * 4);
    unsigned short* Wpk = (unsigned short*)alloc((size_t)112 * 128 * 2);
    unsigned char* hs1  = (unsigned char*)alloc((size_t)N * 64 * 2);    // fp8 [N][64] (region kept 2B/elt wide)
    unsigned short* x1  = (unsigned short*)alloc((size_t)N * 64 * 2);   // bf16 [N][64]
    unsigned short* s02 = (unsigned short*)alloc((size_t)N * 32 * 2);   // bf16 [N][32]
    unsigned short* s03 = (unsigned short*)alloc((size_t)N * 16 * 2);   // bf16 [N][16]
    unsigned short* x2  = (unsigned short*)alloc((size_t)N * 32 * 2);   // bf16 [N][32]
    // aliases over dead regions
    unsigned int* packed = (unsigned int*)x1;           // E*4 = 12.8MB == N*64*2; dead before agg1 writes x1
    unsigned char* hs2 = hs1;                           // fp8 [N][32] in hs1's first N*32 bytes (hs1 dead after agg1)
    unsigned short* s13 = (unsigned short*)(hs1 + (size_t)N * 64);  // bf16 [N][16] in hs1 region's back half
    unsigned char* hs3 = (unsigned char*)s02;           // fp8 [N][16] (s02 dead after agg2)

    // ---- weight prepack (also zeros bcnt) ----
    wpack_kernel<<<(112 * 128 + 255) / 256, 256, 0, stream>>>(W1, Ws02, Ws03, Wpk, bcnt);

    // ---- CSR build ----
    bcount_kernel<<<1024, 256, 0, stream>>>(dst, E, bcnt);
    bscan_kernel<<<1, NB, 0, stream>>>(bcnt, bstart, cursors, E);
    multisplit_kernel<<<(E + 4095) / 4096, 256, 0, stream>>>(src, dst, E, cursors, packed);
    bucket_fill_kernel<<<NB, 256, 0, stream>>>(packed, bstart, N, E, rowptr, col, dinv);

    int gb = (N + 63) / 64;
    // layer 1: one x pass via MFMA -> hs1 (scaled fp8), s02, s03 (bf16)
    mfma3_kernel<<<gb, 256, 0, stream>>>(x, Wpk, dinv, bs02, bs03, hs1, s02, s03, N);
    // agg 1 -> x1 (bf16): F=64, FPL=8 -> 32 nodes/block
    agg_kernel<64, 8, true><<<(N + 31) / 32, 256, 0, stream>>>(hs1, rowptr, col, dinv, b1, nullptr, nullptr, x1, N);
    // layer 2: one x1 pass -> hs2 (scaled fp8), s13 (bf16)
    gemm2b_kernel<64, 32, 16><<<gb, 256, 0, stream>>>(x1, W2, dinv, Ws13, bs13, hs2, s13, N);
    // agg 2 -> x2 (bf16), skip s02: F=32, FPL=8 -> 64 nodes/block
    agg_kernel<32, 8, true><<<(N + 63) / 64, 256, 0, stream>>>(hs2, rowptr, col, dinv, b2, s02, nullptr, x2, N);
    // layer 3
    gemm_l3_kernel<<<gb, 256, 0, stream>>>(x2, W3, dinv, hs3, N);
    // agg 3 -> out (fp32), skips s03 + s13: F=16, FPL=4 -> 64 nodes/block
    agg_kernel<16, 4, false><<<(N + 63) / 64, 256, 0, stream>>>(hs3, rowptr, col, dinv, b3, s03, s13, (float*)d_out, N);
}

// Round 10
// 243.852 us; speedup vs baseline: 1.6962x; 1.0614x over previous
//
#include <hip/hip_runtime.h>

#define NN 100000
#define NB 256            // buckets (fits uint8)
#define NPB 391           // nodes per bucket: ceil(100000/256)=391; local dst fits in 9 bits
#define MSCH 8192         // multisplit chunk (edges per block-iteration)

__device__ inline unsigned short f2bf(float f) {
    unsigned u = __float_as_uint(f);
    return (unsigned short)((u + 0x7FFFu + ((u >> 16) & 1u)) >> 16);
}
__device__ inline unsigned packbf(float a, float b) {
    return (unsigned)f2bf(a) | ((unsigned)f2bf(b) << 16);
}
__device__ inline float bflo(unsigned u) { return __uint_as_float(u << 16); }
__device__ inline float bfhi(unsigned u) { return __uint_as_float(u & 0xFFFF0000u); }
__device__ inline float4 bf4(uint2 u) {
    return make_float4(bflo(u.x), bfhi(u.x), bflo(u.y), bfhi(u.y));
}

// ---- fp8 e4m3 (hardware cvt; encode+decode same HW format -> consistent) ----
__device__ inline void fp8acc(unsigned u, float4& a) {
    auto lo = __builtin_amdgcn_cvt_pk_f32_fp8((int)u, false);
    auto hi = __builtin_amdgcn_cvt_pk_f32_fp8((int)u, true);
    a.x += lo[0]; a.y += lo[1]; a.z += hi[0]; a.w += hi[1];
}
__device__ inline unsigned char f2fp8(float v) {
    return (unsigned char)(__builtin_amdgcn_cvt_pk_fp8_f32(v, 0.f, 0, false) & 0xFF);
}
__device__ inline unsigned short f2fp8x2(float a, float b) {
    return (unsigned short)(__builtin_amdgcn_cvt_pk_fp8_f32(a, b, 0, false) & 0xFFFF);
}

typedef __attribute__((ext_vector_type(8))) short bf16x8;
typedef __attribute__((ext_vector_type(4))) float f32x4;

// ---------------- CSR build: 2-level bucket multisplit ----------------

__global__ __launch_bounds__(256) void bcount_kernel(const int* __restrict__ dst, int E, int* __restrict__ bcnt) {
    __shared__ int h[NB];
    if (threadIdx.x < NB) h[threadIdx.x] = 0;
    __syncthreads();
    for (int e = blockIdx.x * 256 + threadIdx.x; e < E; e += gridDim.x * 256)
        atomicAdd(&h[dst[e] / NPB], 1);
    __syncthreads();
    if (threadIdx.x < NB && h[threadIdx.x]) atomicAdd(&bcnt[threadIdx.x], h[threadIdx.x]);
}

__global__ __launch_bounds__(NB) void bscan_kernel(const int* __restrict__ bcnt, int* __restrict__ bstart,
                                                   int* __restrict__ cursors, int E) {
    __shared__ int sh[NB];
    int t = threadIdx.x;
    int v = bcnt[t];
    sh[t] = v;
    __syncthreads();
    for (int off = 1; off < NB; off <<= 1) {
        int u = (t >= off) ? sh[t - off] : 0;
        __syncthreads();
        sh[t] += u;
        __syncthreads();
    }
    int ex = sh[t] - v;
    bstart[t] = ex;
    cursors[t] = ex;
    if (t == NB - 1) bstart[NB] = E;
}

// LDS-staged multisplit: count+stage chunk -> reserve per-bucket bases -> scatter runs.
// Per chunk each bucket gets ~MSCH/NB = 32 edges = 128B contiguous -> line-dense writes.
__global__ __launch_bounds__(256) void multisplit_kernel(const int* __restrict__ src, const int* __restrict__ dst,
                                                         int E, int* __restrict__ cursors,
                                                         unsigned int* __restrict__ packed) {
    __shared__ unsigned stage_p[MSCH];       // 32 KB: packed (src<<9 | ld)
    __shared__ unsigned char stage_b[MSCH];  // 8 KB: bucket id
    __shared__ int cnt[NB];
    __shared__ int base[NB];
    int t = threadIdx.x;
    for (long c0 = (long)blockIdx.x * MSCH; c0 < E; c0 += (long)gridDim.x * MSCH) {
        if (t < NB) cnt[t] = 0;
        __syncthreads();
        int nE = (int)min((long)MSCH, E - c0);
        for (int k = t; k < nE; k += 256) {
            int d = dst[c0 + k];
            int s = src[c0 + k];
            int b = d / NPB;
            int ld = d - b * NPB;
            atomicAdd(&cnt[b], 1);
            stage_p[k] = ((unsigned)s << 9) | (unsigned)ld;
            stage_b[k] = (unsigned char)b;
        }
        __syncthreads();
        if (t < NB) base[t] = cnt[t] ? atomicAdd(&cursors[t], cnt[t]) : 0;
        __syncthreads();
        for (int k = t; k < nE; k += 256) {
            int b = stage_b[k];
            int pos = atomicAdd(&base[b], 1);
            packed[pos] = stage_p[k];
        }
        __syncthreads();
    }
}

// one block (512 thr) per bucket: LDS hist+scan over NPB local nodes -> rowptr/dinv, cursor fill -> col
__global__ __launch_bounds__(512) void bucket_fill_kernel(const unsigned int* __restrict__ packed,
                                                          const int* __restrict__ bstart, int N, int E,
                                                          int* __restrict__ rowptr, int* __restrict__ col,
                                                          float* __restrict__ dinv) {
    int b = blockIdx.x, t = threadIdx.x;
    int e0 = bstart[b], e1 = bstart[b + 1];
    __shared__ int hist[512];
    __shared__ int sh[512];
    __shared__ int cur[512];
    hist[t] = 0;
    __syncthreads();
    for (int e = e0 + t; e < e1; e += 512)
        atomicAdd(&hist[packed[e] & 511u], 1);
    __syncthreads();
    int v = hist[t];
    sh[t] = v;
    __syncthreads();
    for (int off = 1; off < 512; off <<= 1) {
        int u = (t >= off) ? sh[t - off] : 0;
        __syncthreads();
        sh[t] += u;
        __syncthreads();
    }
    int ex = sh[t] - v;
    int node = b * NPB + t;
    if (t < NPB && node < N) {
        rowptr[node] = e0 + ex;
        dinv[node] = rsqrtf(1.0f + (float)v);
    }
    cur[t] = e0 + ex;
    __syncthreads();
    for (int e = e0 + t; e < e1; e += 512) {
        unsigned int p = packed[e];
        int pos = atomicAdd(&cur[p & 511u], 1);
        col[pos] = (int)(p >> 9);
    }
    if (b == 0 && t == 0) rowptr[N] = E;
}

// ---------------- layer-1 weight prepack: Wpk[c][k] = bf16(W^T), c in [0,112); also zeros bcnt ----

__global__ __launch_bounds__(256) void wpack_kernel(const float* __restrict__ W1, const float* __restrict__ Ws02,
                                                    const float* __restrict__ Ws03, unsigned short* __restrict__ Wpk,
                                                    int* __restrict__ bcnt) {
    if (blockIdx.x == 0) bcnt[threadIdx.x] = 0;
    int i = blockIdx.x * 256 + threadIdx.x;
    if (i >= 112 * 128) return;
    int c = i >> 7, k = i & 127;
    float v;
    if (c < 64)      v = W1[k * 64 + c];
    else if (c < 96) v = Ws02[k * 32 + (c - 64)];
    else             v = Ws03[k * 16 + (c - 96)];
    Wpk[i] = f2bf(v);
}

// ---------------- mfma3: one x pass -> hs1 (64, scaled, fp8), s02 (32, bias, bf16), s03 (16, bias, bf16) ----

__global__ __launch_bounds__(256) void mfma3_kernel(const float* __restrict__ X,
        const unsigned short* __restrict__ Wpk, const float* __restrict__ scale,
        const float* __restrict__ bb, const float* __restrict__ bc,
        unsigned char* __restrict__ oa, unsigned short* __restrict__ ob,
        unsigned short* __restrict__ oc, int N) {
    int t = threadIdx.x;
    int wv = t >> 6, l = t & 63;
    int r0 = blockIdx.x * 64 + wv * 16;
    int col = l & 15, g = l >> 4;
    int rowA = r0 + col;
    bool okA = rowA < N;
    const float* xrow = X + (size_t)rowA * 128;

    f32x4 acc[7];
    #pragma unroll
    for (int i = 0; i < 7; ++i) acc[i] = (f32x4){0.f, 0.f, 0.f, 0.f};

    #pragma unroll
    for (int s = 0; s < 4; ++s) {
        int k0 = s * 32 + g * 8;
        float4 lo = okA ? *(const float4*)(xrow + k0)     : make_float4(0.f, 0.f, 0.f, 0.f);
        float4 hi = okA ? *(const float4*)(xrow + k0 + 4) : make_float4(0.f, 0.f, 0.f, 0.f);
        union { bf16x8 v; unsigned u[4]; } A;
        A.u[0] = packbf(lo.x, lo.y);
        A.u[1] = packbf(lo.z, lo.w);
        A.u[2] = packbf(hi.x, hi.y);
        A.u[3] = packbf(hi.z, hi.w);
        #pragma unroll
        for (int ct = 0; ct < 7; ++ct) {
            bf16x8 B = *(const bf16x8*)(Wpk + ((size_t)(ct * 16 + col) * 128 + k0));
            acc[ct] = __builtin_amdgcn_mfma_f32_16x16x32_bf16(A.v, B, acc[ct], 0, 0, 0);
        }
    }

    #pragma unroll
    for (int v = 0; v < 4; ++v) {
        int row = r0 + g * 4 + v;
        if (row < N) {
            float sc = scale[row];
            #pragma unroll
            for (int ct = 0; ct < 4; ++ct)
                oa[(size_t)row * 64 + ct * 16 + col] = f2fp8(acc[ct][v] * sc);
            #pragma unroll
            for (int ct = 4; ct < 6; ++ct) {
                int c2 = (ct - 4) * 16 + col;
                ob[(size_t)row * 32 + c2] = f2bf(acc[ct][v] + bb[c2]);
            }
            oc[(size_t)row * 16 + col] = f2bf(acc[6][v] + bc[col]);
        }
    }
}

// ---------------- gemm2b: bf16 X input -> hs2 (fp8, scaled), s13 (bf16, bias) ----------------

template <int K, int C1, int C2>
__global__ __launch_bounds__(256) void gemm2b_kernel(const unsigned short* __restrict__ X,
        const float* __restrict__ Wa, const float* __restrict__ scale,
        const float* __restrict__ Wb, const float* __restrict__ bb,
        unsigned char* __restrict__ oa, unsigned short* __restrict__ ob, int N) {
    constexpr int M1 = C1 / 16, M2 = C2 / 16;
    constexpr int XS = K + 6;
    __shared__ float XL[64 * XS];
    __shared__ float WLa[K * C1];
    __shared__ float WLb[K * C2];
    int t = threadIdx.x;
    int r0 = blockIdx.x * 64;

    for (int i = t; i < K * C1 / 4; i += 256) ((float4*)WLa)[i] = ((const float4*)Wa)[i];
    for (int i = t; i < K * C2 / 4; i += 256) ((float4*)WLb)[i] = ((const float4*)Wb)[i];
    for (int i = t; i < 64 * (K / 4); i += 256) {
        int row = i / (K / 4), g = i % (K / 4);
        uint2 u = make_uint2(0u, 0u);
        if (r0 + row < N) u = ((const uint2*)(X + (size_t)(r0 + row) * K))[g];
        float* p = &XL[row * XS + g * 4];
        *(float2*)p = make_float2(bflo(u.x), bfhi(u.x));
        *(float2*)(p + 2) = make_float2(bflo(u.y), bfhi(u.y));
    }
    __syncthreads();

    int ty = t >> 4, tx = t & 15;
    float acc1[4][M1] = {}, acc2[4][M2] = {};
    const float* xb = &XL[(ty * 4) * XS];
    const float* wba = &WLa[tx * M1];
    const float* wbb = &WLb[tx * M2];
    for (int k = 0; k < K; ++k) {
        float x0 = xb[k], x1 = xb[XS + k], x2 = xb[2 * XS + k], x3 = xb[3 * XS + k];
        float wa[M1], wb2[M2];
        #pragma unroll
        for (int j = 0; j < M1; ++j) wa[j] = wba[k * C1 + j];
        #pragma unroll
        for (int j = 0; j < M2; ++j) wb2[j] = wbb[k * C2 + j];
        #pragma unroll
        for (int j = 0; j < M1; ++j) {
            acc1[0][j] = fmaf(x0, wa[j], acc1[0][j]);
            acc1[1][j] = fmaf(x1, wa[j], acc1[1][j]);
            acc1[2][j] = fmaf(x2, wa[j], acc1[2][j]);
            acc1[3][j] = fmaf(x3, wa[j], acc1[3][j]);
        }
        #pragma unroll
        for (int j = 0; j < M2; ++j) {
            acc2[0][j] = fmaf(x0, wb2[j], acc2[0][j]);
            acc2[1][j] = fmaf(x1, wb2[j], acc2[1][j]);
            acc2[2][j] = fmaf(x2, wb2[j], acc2[2][j]);
            acc2[3][j] = fmaf(x3, wb2[j], acc2[3][j]);
        }
    }

    #pragma unroll
    for (int i = 0; i < 4; ++i) {
        int row = r0 + ty * 4 + i;
        if (row < N) {
            float sc = scale[row];
            *(unsigned short*)(oa + (size_t)row * C1 + tx * 2) = f2fp8x2(acc1[i][0] * sc, acc1[i][1] * sc);
            ob[(size_t)row * C2 + tx] = f2bf(acc2[i][0] + bb[tx]);
        }
    }
}

// ---------------- gemm_l3: bf16 X [N][32] -> hs3 [N][16] fp8, scaled ----------------

__global__ __launch_bounds__(256) void gemm_l3_kernel(const unsigned short* __restrict__ X,
        const float* __restrict__ W, const float* __restrict__ scale,
        unsigned char* __restrict__ out, int N) {
    constexpr int K = 32, C = 16, XS = K + 6;
    __shared__ float XL[64 * XS];
    __shared__ float WL[K * C];
    int t = threadIdx.x;
    int r0 = blockIdx.x * 64;

    for (int i = t; i < K * C / 4; i += 256) ((float4*)WL)[i] = ((const float4*)W)[i];
    for (int i = t; i < 64 * (K / 4); i += 256) {
        int row = i / (K / 4), g = i % (K / 4);
        uint2 u = make_uint2(0u, 0u);
        if (r0 + row < N) u = ((const uint2*)(X + (size_t)(r0 + row) * K))[g];
        float* p = &XL[row * XS + g * 4];
        *(float2*)p = make_float2(bflo(u.x), bfhi(u.x));
        *(float2*)(p + 2) = make_float2(bflo(u.y), bfhi(u.y));
    }
    __syncthreads();

    int ty = t >> 4, tx = t & 15;
    float acc[4] = {0.f, 0.f, 0.f, 0.f};
    const float* xb = &XL[(ty * 4) * XS];
    for (int k = 0; k < K; ++k) {
        float wv = WL[k * C + tx];
        acc[0] = fmaf(xb[k], wv, acc[0]);
        acc[1] = fmaf(xb[XS + k], wv, acc[1]);
        acc[2] = fmaf(xb[2 * XS + k], wv, acc[2]);
        acc[3] = fmaf(xb[3 * XS + k], wv, acc[3]);
    }
    #pragma unroll
    for (int i = 0; i < 4; ++i) {
        int row = r0 + ty * 4 + i;
        if (row < N) out[(size_t)row * C + tx] = f2fp8(acc[i] * scale[row]);
    }
}

// ---------------- Aggregation (fp8 hs gather) ----------------

template <int F, int FPL, bool OBF>
__global__ __launch_bounds__(256) void agg_kernel(const unsigned char* __restrict__ hs,
        const int* __restrict__ rowptr, const int* __restrict__ col,
        const float* __restrict__ dinv, const float* __restrict__ bias,
        const unsigned short* __restrict__ skipA, const unsigned short* __restrict__ skipB,
        void* __restrict__ outv, int N) {
    constexpr int VL = F / FPL;
    constexpr int NPW = 64 / VL;
    constexpr int W = 8;
    constexpr int CR = W / VL;
    int t = threadIdx.x;
    int lane = t & 63, wv = t >> 6;
    int sub = lane / VL, fq = lane % VL;
    int i = (blockIdx.x * 4 + wv) * NPW + sub;
    if (i >= N) return;

    float4 aA0 = make_float4(0.f, 0.f, 0.f, 0.f);
    float4 aA1 = make_float4(0.f, 0.f, 0.f, 0.f);
    float4 aB0 = make_float4(0.f, 0.f, 0.f, 0.f);
    float4 aB1 = make_float4(0.f, 0.f, 0.f, 0.f);

    {
        const unsigned char* hrow = hs + (size_t)i * F + fq * FPL;
        if constexpr (FPL == 8) {
            uint2 u = *(const uint2*)hrow;
            fp8acc(u.x, aA0); fp8acc(u.y, aB0);
        } else {
            fp8acc(*(const unsigned*)hrow, aA0);
        }
    }

    int p0 = rowptr[i], p1 = rowptr[i + 1];
    int p = p0;
    for (; p + W <= p1; p += W) {
        int cw[CR];
        #pragma unroll
        for (int j = 0; j < CR; ++j) cw[j] = col[p + fq + j * VL];
        #pragma unroll
        for (int k = 0; k < W; ++k) {
            int s = __shfl(cw[k / VL], k % VL, VL);
            const unsigned char* sp = hs + (size_t)s * F + fq * FPL;
            if constexpr (FPL == 8) {
                uint2 u = *(const uint2*)sp;
                if (k & 1) { fp8acc(u.x, aA1); fp8acc(u.y, aB1); }
                else       { fp8acc(u.x, aA0); fp8acc(u.y, aB0); }
            } else {
                if (k & 1) fp8acc(*(const unsigned*)sp, aA1);
                else       fp8acc(*(const unsigned*)sp, aA0);
            }
        }
    }
    for (; p < p1; p += VL) {
        int c = (p + fq < p1) ? col[p + fq] : 0;
        int m = min(VL, p1 - p);
        for (int k = 0; k < m; ++k) {
            int s = __shfl(c, k, VL);
            const unsigned char* sp = hs + (size_t)s * F + fq * FPL;
            if constexpr (FPL == 8) {
                uint2 u = *(const uint2*)sp;
                fp8acc(u.x, aA1); fp8acc(u.y, aB1);
            } else {
                fp8acc(*(const unsigned*)sp, aA1);
            }
        }
    }

    float di = dinv[i];
    int fb = fq * FPL;
    float o[FPL];
    o[0] = fmaxf(di * (aA0.x + aA1.x) + bias[fb + 0], 0.f);
    o[1] = fmaxf(di * (aA0.y + aA1.y) + bias[fb + 1], 0.f);
    o[2] = fmaxf(di * (aA0.z + aA1.z) + bias[fb + 2], 0.f);
    o[3] = fmaxf(di * (aA0.w + aA1.w) + bias[fb + 3], 0.f);
    if constexpr (FPL == 8) {
        o[4] = fmaxf(di * (aB0.x + aB1.x) + bias[fb + 4], 0.f);
        o[5] = fmaxf(di * (aB0.y + aB1.y) + bias[fb + 5], 0.f);
        o[6] = fmaxf(di * (aB0.z + aB1.z) + bias[fb + 6], 0.f);
        o[7] = fmaxf(di * (aB0.w + aB1.w) + bias[fb + 7], 0.f);
    }
    if (skipA) {
        const unsigned short* sp = skipA + (size_t)i * F + fb;
        if constexpr (FPL == 8) {
            uint4 sa = *(const uint4*)sp;
            float4 s0 = bf4(make_uint2(sa.x, sa.y)), s1 = bf4(make_uint2(sa.z, sa.w));
            o[0] += s0.x; o[1] += s0.y; o[2] += s0.z; o[3] += s0.w;
            o[4] += s1.x; o[5] += s1.y; o[6] += s1.z; o[7] += s1.w;
        } else {
            float4 s0 = bf4(*(const uint2*)sp);
            o[0] += s0.x; o[1] += s0.y; o[2] += s0.z; o[3] += s0.w;
        }
    }
    if (skipB) {
        const unsigned short* sp = skipB + (size_t)i * F + fb;
        if constexpr (FPL == 8) {
            uint4 sa = *(const uint4*)sp;
            float4 s0 = bf4(make_uint2(sa.x, sa.y)), s1 = bf4(make_uint2(sa.z, sa.w));
            o[0] += s0.x; o[1] += s0.y; o[2] += s0.z; o[3] += s0.w;
            o[4] += s1.x; o[5] += s1.y; o[6] += s1.z; o[7] += s1.w;
        } else {
            float4 s0 = bf4(*(const uint2*)sp);
            o[0] += s0.x; o[1] += s0.y; o[2] += s0.z; o[3] += s0.w;
        }
    }

    if constexpr (OBF) {
        unsigned short* op = (unsigned short*)outv + (size_t)i * F + fb;
        if constexpr (FPL == 8) {
            uint4 w4;
            w4.x = packbf(o[0], o[1]); w4.y = packbf(o[2], o[3]);
            w4.z = packbf(o[4], o[5]); w4.w = packbf(o[6], o[7]);
            *(uint4*)op = w4;
        } else {
            uint2 w2;
            w2.x = packbf(o[0], o[1]); w2.y = packbf(o[2], o[3]);
            *(uint2*)op = w2;
        }
    } else {
        *(float4*)((float*)outv + (size_t)i * F + fb) = make_float4(o[0], o[1], o[2], o[3]);
    }
}

// ---------------- launch ----------------

extern "C" void kernel_launch(void* const* d_in, const int* in_sizes, int n_in,
                              void* d_out, int out_size, void* d_ws, size_t ws_size,
                              hipStream_t stream) {
    const int N = NN;
    const float* x   = (const float*)d_in[0];
    const int*   ei  = (const int*)d_in[1];
    const int    E   = in_sizes[1] / 2;
    const int*   src = ei;
    const int*   dst = ei + E;
    const float* W1 = (const float*)d_in[2],  *b1  = (const float*)d_in[3];
    const float* W2 = (const float*)d_in[4],  *b2  = (const float*)d_in[5];
    const float* W3 = (const float*)d_in[6],  *b3  = (const float*)d_in[7];
    const float* Ws02 = (const float*)d_in[8],  *bs02 = (const float*)d_in[9];
    const float* Ws03 = (const float*)d_in[10], *bs03 = (const float*)d_in[11];
    const float* Ws13 = (const float*)d_in[12], *bs13 = (const float*)d_in[13];

    char* w = (char*)d_ws;
    size_t off = 0;
    auto alloc = [&](size_t bytes) -> void* {
        void* p = w + off;
        off += (bytes + 255) & ~(size_t)255;
        return p;
    };
    int*   bcnt     = (int*)alloc((size_t)NB * 4);
    int*   bstart   = (int*)alloc((size_t)(NB + 1) * 4);
    int*   cursors  = (int*)alloc((size_t)NB * 4);
    int*   rowptr   = (int*)alloc(((size_t)N + 1) * 4);
    float* dinv     = (float*)alloc((size_t)N * 4);
    int*   col      = (int*)alloc((size_t)E * 4);
    unsigned short* Wpk = (unsigned short*)alloc((size_t)112 * 128 * 2);
    unsigned char* hs1  = (unsigned char*)alloc((size_t)N * 64 * 2);    // fp8 [N][64] (region 2B/elt wide)
    unsigned short* x1  = (unsigned short*)alloc((size_t)N * 64 * 2);   // bf16 [N][64]
    unsigned short* s02 = (unsigned short*)alloc((size_t)N * 32 * 2);   // bf16 [N][32]
    unsigned short* s03 = (unsigned short*)alloc((size_t)N * 16 * 2);   // bf16 [N][16]
    unsigned short* x2  = (unsigned short*)alloc((size_t)N * 32 * 2);   // bf16 [N][32]
    // aliases over dead regions
    unsigned int* packed = (unsigned int*)x1;           // dead before agg1 writes x1
    unsigned char* hs2 = hs1;                           // fp8 [N][32] (hs1 dead after agg1)
    unsigned short* s13 = (unsigned short*)(hs1 + (size_t)N * 64);  // bf16 [N][16] in hs1 region back half
    unsigned char* hs3 = (unsigned char*)s02;           // fp8 [N][16] (s02 dead after agg2)

    // ---- weight prepack (also zeros bcnt) ----
    wpack_kernel<<<(112 * 128 + 255) / 256, 256, 0, stream>>>(W1, Ws02, Ws03, Wpk, bcnt);

    // ---- CSR build ----
    bcount_kernel<<<1024, 256, 0, stream>>>(dst, E, bcnt);
    bscan_kernel<<<1, NB, 0, stream>>>(bcnt, bstart, cursors, E);
    multisplit_kernel<<<(E + MSCH - 1) / MSCH, 256, 0, stream>>>(src, dst, E, cursors, packed);
    bucket_fill_kernel<<<NB, 512, 0, stream>>>(packed, bstart, N, E, rowptr, col, dinv);

    int gb = (N + 63) / 64;
    // layer 1: one x pass via MFMA -> hs1 (scaled fp8), s02, s03 (bf16)
    mfma3_kernel<<<gb, 256, 0, stream>>>(x, Wpk, dinv, bs02, bs03, hs1, s02, s03, N);
    // agg 1 -> x1 (bf16)
    agg_kernel<64, 8, true><<<(N + 31) / 32, 256, 0, stream>>>(hs1, rowptr, col, dinv, b1, nullptr, nullptr, x1, N);
    // layer 2: one x1 pass -> hs2 (scaled fp8), s13 (bf16)
    gemm2b_kernel<64, 32, 16><<<gb, 256, 0, stream>>>(x1, W2, dinv, Ws13, bs13, hs2, s13, N);
    // agg 2 -> x2 (bf16), skip s02
    agg_kernel<32, 8, true><<<(N + 63) / 64, 256, 0, stream>>>(hs2, rowptr, col, dinv, b2, s02, nullptr, x2, N);
    // layer 3
    gemm_l3_kernel<<<gb, 256, 0, stream>>>(x2, W3, dinv, hs3, N);
    // agg 3 -> out (fp32), skips s03 + s13
    agg_kernel<16, 4, false><<<(N + 63) / 64, 256, 0, stream>>>(hs3, rowptr, col, dinv, b3, s03, s13, (float*)d_out, N);
}

// Round 11
// 238.509 us; speedup vs baseline: 1.7342x; 1.0224x over previous
//
#include <hip/hip_runtime.h>

#define NN 100000
#define NB 256            // buckets (fits uint8)
#define NPB 391           // nodes per bucket: ceil(100000/256)=391; local dst fits in 9 bits
#define MSCH 8192         // multisplit chunk (edges per block-iteration)

__device__ inline unsigned short f2bf(float f) {
    unsigned u = __float_as_uint(f);
    return (unsigned short)((u + 0x7FFFu + ((u >> 16) & 1u)) >> 16);
}
__device__ inline unsigned packbf(float a, float b) {
    return (unsigned)f2bf(a) | ((unsigned)f2bf(b) << 16);
}
__device__ inline float bflo(unsigned u) { return __uint_as_float(u << 16); }
__device__ inline float bfhi(unsigned u) { return __uint_as_float(u & 0xFFFF0000u); }
__device__ inline float4 bf4(uint2 u) {
    return make_float4(bflo(u.x), bfhi(u.x), bflo(u.y), bfhi(u.y));
}

// ---- fp8 e4m3 (hardware cvt; encode+decode same HW format -> consistent) ----
__device__ inline void fp8acc(unsigned u, float4& a) {
    auto lo = __builtin_amdgcn_cvt_pk_f32_fp8((int)u, false);
    auto hi = __builtin_amdgcn_cvt_pk_f32_fp8((int)u, true);
    a.x += lo[0]; a.y += lo[1]; a.z += hi[0]; a.w += hi[1];
}
__device__ inline unsigned char f2fp8(float v) {
    return (unsigned char)(__builtin_amdgcn_cvt_pk_fp8_f32(v, 0.f, 0, false) & 0xFF);
}
__device__ inline unsigned short f2fp8x2(float a, float b) {
    return (unsigned short)(__builtin_amdgcn_cvt_pk_fp8_f32(a, b, 0, false) & 0xFFFF);
}

typedef __attribute__((ext_vector_type(8))) short bf16x8;
typedef __attribute__((ext_vector_type(4))) float f32x4;

// ---------------- CSR build: 2-level bucket multisplit ----------------

__global__ __launch_bounds__(256) void bcount_kernel(const int* __restrict__ dst, int E, int* __restrict__ bcnt) {
    __shared__ int h[NB];
    if (threadIdx.x < NB) h[threadIdx.x] = 0;
    __syncthreads();
    for (int e = blockIdx.x * 256 + threadIdx.x; e < E; e += gridDim.x * 256)
        atomicAdd(&h[dst[e] / NPB], 1);
    __syncthreads();
    if (threadIdx.x < NB && h[threadIdx.x]) atomicAdd(&bcnt[threadIdx.x], h[threadIdx.x]);
}

__global__ __launch_bounds__(NB) void bscan_kernel(const int* __restrict__ bcnt, int* __restrict__ bstart,
                                                   int* __restrict__ cursors, int E) {
    __shared__ int sh[NB];
    int t = threadIdx.x;
    int v = bcnt[t];
    sh[t] = v;
    __syncthreads();
    for (int off = 1; off < NB; off <<= 1) {
        int u = (t >= off) ? sh[t - off] : 0;
        __syncthreads();
        sh[t] += u;
        __syncthreads();
    }
    int ex = sh[t] - v;
    bstart[t] = ex;
    cursors[t] = ex;
    if (t == NB - 1) bstart[NB] = E;
}

// LDS-staged multisplit: count+stage chunk -> reserve per-bucket bases -> scatter runs.
__global__ __launch_bounds__(256) void multisplit_kernel(const int* __restrict__ src, const int* __restrict__ dst,
                                                         int E, int* __restrict__ cursors,
                                                         unsigned int* __restrict__ packed) {
    __shared__ unsigned stage_p[MSCH];
    __shared__ unsigned char stage_b[MSCH];
    __shared__ int cnt[NB];
    __shared__ int base[NB];
    int t = threadIdx.x;
    for (long c0 = (long)blockIdx.x * MSCH; c0 < E; c0 += (long)gridDim.x * MSCH) {
        if (t < NB) cnt[t] = 0;
        __syncthreads();
        int nE = (int)min((long)MSCH, E - c0);
        for (int k = t; k < nE; k += 256) {
            int d = dst[c0 + k];
            int s = src[c0 + k];
            int b = d / NPB;
            int ld = d - b * NPB;
            atomicAdd(&cnt[b], 1);
            stage_p[k] = ((unsigned)s << 9) | (unsigned)ld;
            stage_b[k] = (unsigned char)b;
        }
        __syncthreads();
        if (t < NB) base[t] = cnt[t] ? atomicAdd(&cursors[t], cnt[t]) : 0;
        __syncthreads();
        for (int k = t; k < nE; k += 256) {
            int b = stage_b[k];
            int pos = atomicAdd(&base[b], 1);
            packed[pos] = stage_p[k];
        }
        __syncthreads();
    }
}

__global__ __launch_bounds__(512) void bucket_fill_kernel(const unsigned int* __restrict__ packed,
                                                          const int* __restrict__ bstart, int N, int E,
                                                          int* __restrict__ rowptr, int* __restrict__ col,
                                                          float* __restrict__ dinv) {
    int b = blockIdx.x, t = threadIdx.x;
    int e0 = bstart[b], e1 = bstart[b + 1];
    __shared__ int hist[512];
    __shared__ int sh[512];
    __shared__ int cur[512];
    hist[t] = 0;
    __syncthreads();
    for (int e = e0 + t; e < e1; e += 512)
        atomicAdd(&hist[packed[e] & 511u], 1);
    __syncthreads();
    int v = hist[t];
    sh[t] = v;
    __syncthreads();
    for (int off = 1; off < 512; off <<= 1) {
        int u = (t >= off) ? sh[t - off] : 0;
        __syncthreads();
        sh[t] += u;
        __syncthreads();
    }
    int ex = sh[t] - v;
    int node = b * NPB + t;
    if (t < NPB && node < N) {
        rowptr[node] = e0 + ex;
        dinv[node] = rsqrtf(1.0f + (float)v);
    }
    cur[t] = e0 + ex;
    __syncthreads();
    for (int e = e0 + t; e < e1; e += 512) {
        unsigned int p = packed[e];
        int pos = atomicAdd(&cur[p & 511u], 1);
        col[pos] = (int)(p >> 9);
    }
    if (b == 0 && t == 0) rowptr[N] = E;
}

// ---------------- layer-1 weight prepack: Wpk[c][k] = bf16(W^T), c in [0,112); also zeros bcnt ----

__global__ __launch_bounds__(256) void wpack_kernel(const float* __restrict__ W1, const float* __restrict__ Ws02,
                                                    const float* __restrict__ Ws03, unsigned short* __restrict__ Wpk,
                                                    int* __restrict__ bcnt) {
    if (blockIdx.x == 0) bcnt[threadIdx.x] = 0;
    int i = blockIdx.x * 256 + threadIdx.x;
    if (i >= 112 * 128) return;
    int c = i >> 7, k = i & 127;
    float v;
    if (c < 64)      v = W1[k * 64 + c];
    else if (c < 96) v = Ws02[k * 32 + (c - 64)];
    else             v = Ws03[k * 16 + (c - 96)];
    Wpk[i] = f2bf(v);
}

// ---------------- mfma3: one x pass -> hs1 (64, scaled, fp8), s02 (32, bias, bf16), s03 (16, bias, bf16) ----
// 2 row-tiles per wave (32 rows) sharing B-fragments: 16 independent x-loads in flight,
// half the B-load traffic. Block covers 128 rows.

__global__ __launch_bounds__(256) void mfma3_kernel(const float* __restrict__ X,
        const unsigned short* __restrict__ Wpk, const float* __restrict__ scale,
        const float* __restrict__ bb, const float* __restrict__ bc,
        unsigned char* __restrict__ oa, unsigned short* __restrict__ ob,
        unsigned short* __restrict__ oc, int N) {
    int t = threadIdx.x;
    int wv = t >> 6, l = t & 63;
    int r0 = blockIdx.x * 128 + wv * 32;
    int col = l & 15, g = l >> 4;
    int rowA0 = r0 + col, rowA1 = r0 + 16 + col;
    bool ok0 = rowA0 < N, ok1 = rowA1 < N;
    const float* xr0 = X + (size_t)rowA0 * 128;
    const float* xr1 = X + (size_t)rowA1 * 128;

    f32x4 acc[2][7];
    #pragma unroll
    for (int ti = 0; ti < 2; ++ti)
        #pragma unroll
        for (int i = 0; i < 7; ++i) acc[ti][i] = (f32x4){0.f, 0.f, 0.f, 0.f};

    #pragma unroll
    for (int s = 0; s < 4; ++s) {
        int k0 = s * 32 + g * 8;
        float4 lo0 = ok0 ? *(const float4*)(xr0 + k0)     : make_float4(0.f, 0.f, 0.f, 0.f);
        float4 hi0 = ok0 ? *(const float4*)(xr0 + k0 + 4) : make_float4(0.f, 0.f, 0.f, 0.f);
        float4 lo1 = ok1 ? *(const float4*)(xr1 + k0)     : make_float4(0.f, 0.f, 0.f, 0.f);
        float4 hi1 = ok1 ? *(const float4*)(xr1 + k0 + 4) : make_float4(0.f, 0.f, 0.f, 0.f);
        union { bf16x8 v; unsigned u[4]; } A0, A1;
        A0.u[0] = packbf(lo0.x, lo0.y); A0.u[1] = packbf(lo0.z, lo0.w);
        A0.u[2] = packbf(hi0.x, hi0.y); A0.u[3] = packbf(hi0.z, hi0.w);
        A1.u[0] = packbf(lo1.x, lo1.y); A1.u[1] = packbf(lo1.z, lo1.w);
        A1.u[2] = packbf(hi1.x, hi1.y); A1.u[3] = packbf(hi1.z, hi1.w);
        #pragma unroll
        for (int ct = 0; ct < 7; ++ct) {
            bf16x8 B = *(const bf16x8*)(Wpk + ((size_t)(ct * 16 + col) * 128 + k0));
            acc[0][ct] = __builtin_amdgcn_mfma_f32_16x16x32_bf16(A0.v, B, acc[0][ct], 0, 0, 0);
            acc[1][ct] = __builtin_amdgcn_mfma_f32_16x16x32_bf16(A1.v, B, acc[1][ct], 0, 0, 0);
        }
    }

    #pragma unroll
    for (int ti = 0; ti < 2; ++ti) {
        #pragma unroll
        for (int v = 0; v < 4; ++v) {
            int row = r0 + ti * 16 + g * 4 + v;
            if (row < N) {
                float sc = scale[row];
                #pragma unroll
                for (int ct = 0; ct < 4; ++ct)
                    oa[(size_t)row * 64 + ct * 16 + col] = f2fp8(acc[ti][ct][v] * sc);
                #pragma unroll
                for (int ct = 4; ct < 6; ++ct) {
                    int c2 = (ct - 4) * 16 + col;
                    ob[(size_t)row * 32 + c2] = f2bf(acc[ti][ct][v] + bb[c2]);
                }
                oc[(size_t)row * 16 + col] = f2bf(acc[ti][6][v] + bc[col]);
            }
        }
    }
}

// ---------------- gemm2b: bf16 X input -> hs2 (fp8, scaled), s13 (bf16, bias) ----------------

template <int K, int C1, int C2>
__global__ __launch_bounds__(256) void gemm2b_kernel(const unsigned short* __restrict__ X,
        const float* __restrict__ Wa, const float* __restrict__ scale,
        const float* __restrict__ Wb, const float* __restrict__ bb,
        unsigned char* __restrict__ oa, unsigned short* __restrict__ ob, int N) {
    constexpr int M1 = C1 / 16, M2 = C2 / 16;
    constexpr int XS = K + 6;
    __shared__ float XL[64 * XS];
    __shared__ float WLa[K * C1];
    __shared__ float WLb[K * C2];
    int t = threadIdx.x;
    int r0 = blockIdx.x * 64;

    for (int i = t; i < K * C1 / 4; i += 256) ((float4*)WLa)[i] = ((const float4*)Wa)[i];
    for (int i = t; i < K * C2 / 4; i += 256) ((float4*)WLb)[i] = ((const float4*)Wb)[i];
    for (int i = t; i < 64 * (K / 4); i += 256) {
        int row = i / (K / 4), g = i % (K / 4);
        uint2 u = make_uint2(0u, 0u);
        if (r0 + row < N) u = ((const uint2*)(X + (size_t)(r0 + row) * K))[g];
        float* p = &XL[row * XS + g * 4];
        *(float2*)p = make_float2(bflo(u.x), bfhi(u.x));
        *(float2*)(p + 2) = make_float2(bflo(u.y), bfhi(u.y));
    }
    __syncthreads();

    int ty = t >> 4, tx = t & 15;
    float acc1[4][M1] = {}, acc2[4][M2] = {};
    const float* xb = &XL[(ty * 4) * XS];
    const float* wba = &WLa[tx * M1];
    const float* wbb = &WLb[tx * M2];
    for (int k = 0; k < K; ++k) {
        float x0 = xb[k], x1 = xb[XS + k], x2 = xb[2 * XS + k], x3 = xb[3 * XS + k];
        float wa[M1], wb2[M2];
        #pragma unroll
        for (int j = 0; j < M1; ++j) wa[j] = wba[k * C1 + j];
        #pragma unroll
        for (int j = 0; j < M2; ++j) wb2[j] = wbb[k * C2 + j];
        #pragma unroll
        for (int j = 0; j < M1; ++j) {
            acc1[0][j] = fmaf(x0, wa[j], acc1[0][j]);
            acc1[1][j] = fmaf(x1, wa[j], acc1[1][j]);
            acc1[2][j] = fmaf(x2, wa[j], acc1[2][j]);
            acc1[3][j] = fmaf(x3, wa[j], acc1[3][j]);
        }
        #pragma unroll
        for (int j = 0; j < M2; ++j) {
            acc2[0][j] = fmaf(x0, wb2[j], acc2[0][j]);
            acc2[1][j] = fmaf(x1, wb2[j], acc2[1][j]);
            acc2[2][j] = fmaf(x2, wb2[j], acc2[2][j]);
            acc2[3][j] = fmaf(x3, wb2[j], acc2[3][j]);
        }
    }

    #pragma unroll
    for (int i = 0; i < 4; ++i) {
        int row = r0 + ty * 4 + i;
        if (row < N) {
            float sc = scale[row];
            *(unsigned short*)(oa + (size_t)row * C1 + tx * 2) = f2fp8x2(acc1[i][0] * sc, acc1[i][1] * sc);
            ob[(size_t)row * C2 + tx] = f2bf(acc2[i][0] + bb[tx]);
        }
    }
}

// ---------------- gemm_l3: bf16 X [N][32] -> hs3 [N][16] fp8, scaled ----------------

__global__ __launch_bounds__(256) void gemm_l3_kernel(const unsigned short* __restrict__ X,
        const float* __restrict__ W, const float* __restrict__ scale,
        unsigned char* __restrict__ out, int N) {
    constexpr int K = 32, C = 16, XS = K + 6;
    __shared__ float XL[64 * XS];
    __shared__ float WL[K * C];
    int t = threadIdx.x;
    int r0 = blockIdx.x * 64;

    for (int i = t; i < K * C / 4; i += 256) ((float4*)WL)[i] = ((const float4*)W)[i];
    for (int i = t; i < 64 * (K / 4); i += 256) {
        int row = i / (K / 4), g = i % (K / 4);
        uint2 u = make_uint2(0u, 0u);
        if (r0 + row < N) u = ((const uint2*)(X + (size_t)(r0 + row) * K))[g];
        float* p = &XL[row * XS + g * 4];
        *(float2*)p = make_float2(bflo(u.x), bfhi(u.x));
        *(float2*)(p + 2) = make_float2(bflo(u.y), bfhi(u.y));
    }
    __syncthreads();

    int ty = t >> 4, tx = t & 15;
    float acc[4] = {0.f, 0.f, 0.f, 0.f};
    const float* xb = &XL[(ty * 4) * XS];
    for (int k = 0; k < K; ++k) {
        float wv = WL[k * C + tx];
        acc[0] = fmaf(xb[k], wv, acc[0]);
        acc[1] = fmaf(xb[XS + k], wv, acc[1]);
        acc[2] = fmaf(xb[2 * XS + k], wv, acc[2]);
        acc[3] = fmaf(xb[3 * XS + k], wv, acc[3]);
    }
    #pragma unroll
    for (int i = 0; i < 4; ++i) {
        int row = r0 + ty * 4 + i;
        if (row < N) out[(size_t)row * C + tx] = f2fp8(acc[i] * scale[row]);
    }
}

// ---------------- Aggregation (fp8 hs gather) ----------------

template <int F, int FPL, bool OBF>
__global__ __launch_bounds__(256) void agg_kernel(const unsigned char* __restrict__ hs,
        const int* __restrict__ rowptr, const int* __restrict__ col,
        const float* __restrict__ dinv, const float* __restrict__ bias,
        const unsigned short* __restrict__ skipA, const unsigned short* __restrict__ skipB,
        void* __restrict__ outv, int N) {
    constexpr int VL = F / FPL;
    constexpr int NPW = 64 / VL;
    constexpr int W = 8;
    constexpr int CR = W / VL;
    int t = threadIdx.x;
    int lane = t & 63, wv = t >> 6;
    int sub = lane / VL, fq = lane % VL;
    int i = (blockIdx.x * 4 + wv) * NPW + sub;
    if (i >= N) return;

    float4 aA0 = make_float4(0.f, 0.f, 0.f, 0.f);
    float4 aA1 = make_float4(0.f, 0.f, 0.f, 0.f);
    float4 aB0 = make_float4(0.f, 0.f, 0.f, 0.f);
    float4 aB1 = make_float4(0.f, 0.f, 0.f, 0.f);

    {
        const unsigned char* hrow = hs + (size_t)i * F + fq * FPL;
        if constexpr (FPL == 8) {
            uint2 u = *(const uint2*)hrow;
            fp8acc(u.x, aA0); fp8acc(u.y, aB0);
        } else {
            fp8acc(*(const unsigned*)hrow, aA0);
        }
    }

    int p0 = rowptr[i], p1 = rowptr[i + 1];
    int p = p0;
    for (; p + W <= p1; p += W) {
        int cw[CR];
        #pragma unroll
        for (int j = 0; j < CR; ++j) cw[j] = col[p + fq + j * VL];
        #pragma unroll
        for (int k = 0; k < W; ++k) {
            int s = __shfl(cw[k / VL], k % VL, VL);
            const unsigned char* sp = hs + (size_t)s * F + fq * FPL;
            if constexpr (FPL == 8) {
                uint2 u = *(const uint2*)sp;
                if (k & 1) { fp8acc(u.x, aA1); fp8acc(u.y, aB1); }
                else       { fp8acc(u.x, aA0); fp8acc(u.y, aB0); }
            } else {
                if (k & 1) fp8acc(*(const unsigned*)sp, aA1);
                else       fp8acc(*(const unsigned*)sp, aA0);
            }
        }
    }
    for (; p < p1; p += VL) {
        int c = (p + fq < p1) ? col[p + fq] : 0;
        int m = min(VL, p1 - p);
        for (int k = 0; k < m; ++k) {
            int s = __shfl(c, k, VL);
            const unsigned char* sp = hs + (size_t)s * F + fq * FPL;
            if constexpr (FPL == 8) {
                uint2 u = *(const uint2*)sp;
                fp8acc(u.x, aA1); fp8acc(u.y, aB1);
            } else {
                fp8acc(*(const unsigned*)sp, aA1);
            }
        }
    }

    float di = dinv[i];
    int fb = fq * FPL;
    float o[FPL];
    o[0] = fmaxf(di * (aA0.x + aA1.x) + bias[fb + 0], 0.f);
    o[1] = fmaxf(di * (aA0.y + aA1.y) + bias[fb + 1], 0.f);
    o[2] = fmaxf(di * (aA0.z + aA1.z) + bias[fb + 2], 0.f);
    o[3] = fmaxf(di * (aA0.w + aA1.w) + bias[fb + 3], 0.f);
    if constexpr (FPL == 8) {
        o[4] = fmaxf(di * (aB0.x + aB1.x) + bias[fb + 4], 0.f);
        o[5] = fmaxf(di * (aB0.y + aB1.y) + bias[fb + 5], 0.f);
        o[6] = fmaxf(di * (aB0.z + aB1.z) + bias[fb + 6], 0.f);
        o[7] = fmaxf(di * (aB0.w + aB1.w) + bias[fb + 7], 0.f);
    }
    if (skipA) {
        const unsigned short* sp = skipA + (size_t)i * F + fb;
        if constexpr (FPL == 8) {
            uint4 sa = *(const uint4*)sp;
            float4 s0 = bf4(make_uint2(sa.x, sa.y)), s1 = bf4(make_uint2(sa.z, sa.w));
            o[0] += s0.x; o[1] += s0.y; o[2] += s0.z; o[3] += s0.w;
            o[4] += s1.x; o[5] += s1.y; o[6] += s1.z; o[7] += s1.w;
        } else {
            float4 s0 = bf4(*(const uint2*)sp);
            o[0] += s0.x; o[1] += s0.y; o[2] += s0.z; o[3] += s0.w;
        }
    }
    if (skipB) {
        const unsigned short* sp = skipB + (size_t)i * F + fb;
        if constexpr (FPL == 8) {
            uint4 sa = *(const uint4*)sp;
            float4 s0 = bf4(make_uint2(sa.x, sa.y)), s1 = bf4(make_uint2(sa.z, sa.w));
            o[0] += s0.x; o[1] += s0.y; o[2] += s0.z; o[3] += s0.w;
            o[4] += s1.x; o[5] += s1.y; o[6] += s1.z; o[7] += s1.w;
        } else {
            float4 s0 = bf4(*(const uint2*)sp);
            o[0] += s0.x; o[1] += s0.y; o[2] += s0.z; o[3] += s0.w;
        }
    }

    if constexpr (OBF) {
        unsigned short* op = (unsigned short*)outv + (size_t)i * F + fb;
        if constexpr (FPL == 8) {
            uint4 w4;
            w4.x = packbf(o[0], o[1]); w4.y = packbf(o[2], o[3]);
            w4.z = packbf(o[4], o[5]); w4.w = packbf(o[6], o[7]);
            *(uint4*)op = w4;
        } else {
            uint2 w2;
            w2.x = packbf(o[0], o[1]); w2.y = packbf(o[2], o[3]);
            *(uint2*)op = w2;
        }
    } else {
        *(float4*)((float*)outv + (size_t)i * F + fb) = make_float4(o[0], o[1], o[2], o[3]);
    }
}

// ---------------- launch ----------------

extern "C" void kernel_launch(void* const* d_in, const int* in_sizes, int n_in,
                              void* d_out, int out_size, void* d_ws, size_t ws_size,
                              hipStream_t stream) {
    const int N = NN;
    const float* x   = (const float*)d_in[0];
    const int*   ei  = (const int*)d_in[1];
    const int    E   = in_sizes[1] / 2;
    const int*   src = ei;
    const int*   dst = ei + E;
    const float* W1 = (const float*)d_in[2],  *b1  = (const float*)d_in[3];
    const float* W2 = (const float*)d_in[4],  *b2  = (const float*)d_in[5];
    const float* W3 = (const float*)d_in[6],  *b3  = (const float*)d_in[7];
    const float* Ws02 = (const float*)d_in[8],  *bs02 = (const float*)d_in[9];
    const float* Ws03 = (const float*)d_in[10], *bs03 = (const float*)d_in[11];
    const float* Ws13 = (const float*)d_in[12], *bs13 = (const float*)d_in[13];

    char* w = (char*)d_ws;
    size_t off = 0;
    auto alloc = [&](size_t bytes) -> void* {
        void* p = w + off;
        off += (bytes + 255) & ~(size_t)255;
        return p;
    };
    int*   bcnt     = (int*)alloc((size_t)NB * 4);
    int*   bstart   = (int*)alloc((size_t)(NB + 1) * 4);
    int*   cursors  = (int*)alloc((size_t)NB * 4);
    int*   rowptr   = (int*)alloc(((size_t)N + 1) * 4);
    float* dinv     = (float*)alloc((size_t)N * 4);
    int*   col      = (int*)alloc((size_t)E * 4);
    unsigned short* Wpk = (unsigned short*)alloc((size_t)112 * 128 * 2);
    unsigned char* hs1  = (unsigned char*)alloc((size_t)N * 64 * 2);    // fp8 [N][64] (region 2B/elt wide)
    unsigned short* x1  = (unsigned short*)alloc((size_t)N * 64 * 2);   // bf16 [N][64]
    unsigned short* s02 = (unsigned short*)alloc((size_t)N * 32 * 2);   // bf16 [N][32]
    unsigned short* s03 = (unsigned short*)alloc((size_t)N * 16 * 2);   // bf16 [N][16]
    unsigned short* x2  = (unsigned short*)alloc((size_t)N * 32 * 2);   // bf16 [N][32]
    // aliases over dead regions
    unsigned int* packed = (unsigned int*)x1;           // dead before agg1 writes x1
    unsigned char* hs2 = hs1;                           // fp8 [N][32] (hs1 dead after agg1)
    unsigned short* s13 = (unsigned short*)(hs1 + (size_t)N * 64);  // bf16 [N][16] in hs1 region back half
    unsigned char* hs3 = (unsigned char*)s02;           // fp8 [N][16] (s02 dead after agg2)

    // ---- weight prepack (also zeros bcnt) ----
    wpack_kernel<<<(112 * 128 + 255) / 256, 256, 0, stream>>>(W1, Ws02, Ws03, Wpk, bcnt);

    // ---- CSR build ----
    bcount_kernel<<<1024, 256, 0, stream>>>(dst, E, bcnt);
    bscan_kernel<<<1, NB, 0, stream>>>(bcnt, bstart, cursors, E);
    multisplit_kernel<<<(E + MSCH - 1) / MSCH, 256, 0, stream>>>(src, dst, E, cursors, packed);
    bucket_fill_kernel<<<NB, 512, 0, stream>>>(packed, bstart, N, E, rowptr, col, dinv);

    int gb = (N + 63) / 64;
    // layer 1: one x pass via MFMA (2 tiles/wave) -> hs1 (scaled fp8), s02, s03 (bf16)
    mfma3_kernel<<<(N + 127) / 128, 256, 0, stream>>>(x, Wpk, dinv, bs02, bs03, hs1, s02, s03, N);
    // agg 1 -> x1 (bf16)
    agg_kernel<64, 8, true><<<(N + 31) / 32, 256, 0, stream>>>(hs1, rowptr, col, dinv, b1, nullptr, nullptr, x1, N);
    // layer 2: one x1 pass -> hs2 (scaled fp8), s13 (bf16)
    gemm2b_kernel<64, 32, 16><<<gb, 256, 0, stream>>>(x1, W2, dinv, Ws13, bs13, hs2, s13, N);
    // agg 2 -> x2 (bf16), skip s02
    agg_kernel<32, 8, true><<<(N + 63) / 64, 256, 0, stream>>>(hs2, rowptr, col, dinv, b2, s02, nullptr, x2, N);
    // layer 3
    gemm_l3_kernel<<<gb, 256, 0, stream>>>(x2, W3, dinv, hs3, N);
    // agg 3 -> out (fp32), skips s03 + s13
    agg_kernel<16, 4, false><<<(N + 63) / 64, 256, 0, stream>>>(hs3, rowptr, col, dinv, b3, s03, s13, (float*)d_out, N);
}